// Round 1
// baseline (39738.254 us; speedup 1.0000x reference)
//
#include <hip/hip_runtime.h>
#include <math.h>

#define NNODES 10000
#define NEDGES 131072

// ws layout (in floats)
#define W3J_OFF 0                     // 10 * 128
#define H_OFF   1280                  // NNODES * 512
#define CAT_OFF (1280 + NNODES*512)   // NNODES * 5120
// cat per-node layout: l3=0 @0 (2*128*1), l3=1 @256 (3*128*3), l3=2 @1408 (3*128*5), l3=3 @3328 (2*128*7)

// ---------------------------------------------------------------- w3j kernel
struct cpx { double re, im; };
__device__ inline cpx cmul(cpx a, cpx b){ return {a.re*b.re - a.im*b.im, a.re*b.im + a.im*b.re}; }

__device__ double dfact(int n){ double r = 1.0; for (int i = 2; i <= n; ++i) r *= (double)i; return r; }

__device__ double cgval(int j1,int j2,int j3,int m1,int m2){
  int m3 = m1 + m2;
  if (m3 > j3 || m3 < -j3) return 0.0;
  double pref = (double)(2*j3+1) * dfact(j3+j1-j2)*dfact(j3-j1+j2)*dfact(j1+j2-j3)/dfact(j1+j2+j3+1);
  pref *= dfact(j3+m3)*dfact(j3-m3)*dfact(j1-m1)*dfact(j1+m1)*dfact(j2-m2)*dfact(j2+m2);
  int k0 = 0; if (-(j3-j2+m1) > k0) k0 = -(j3-j2+m1); if (-(j3-j1-m2) > k0) k0 = -(j3-j1-m2);
  int k1 = j1+j2-j3; if (j1-m1 < k1) k1 = j1-m1; if (j2+m2 < k1) k1 = j2+m2;
  double s = 0.0;
  for (int k = k0; k <= k1; ++k){
    double d = dfact(k)*dfact(j1+j2-j3-k)*dfact(j1-m1-k)*dfact(j2+m2-k)*dfact(j3-j2+m1+k)*dfact(j3-j1-m2+k);
    s += ((k & 1) ? -1.0 : 1.0) / d;
  }
  return sqrt(pref) * s;
}

__device__ cpx qval(int l, int a, int col){
  int m = a - l;
  const double is2 = 0.70710678118654752440;
  double re = 0.0, im = 0.0;
  if (m < 0){
    if (col == l - m) re = is2;          // l + |m|
    else if (col == l + m) im = -is2;    // l - |m|
  } else if (m == 0){
    if (col == l) re = 1.0;
  } else {
    double sgn = (m & 1) ? -1.0 : 1.0;
    if (col == l + m) re = sgn * is2;
    else if (col == l - m) im = sgn * is2;
  }
  double pr, pi;  // (-i)^l
  switch (l & 3){ case 0: pr=1; pi=0; break; case 1: pr=0; pi=-1; break; case 2: pr=-1; pi=0; break; default: pr=0; pi=1; }
  return { re*pr - im*pi, re*pi + im*pr };
}

__global__ void w3j_kernel(float* ws){
  __shared__ double red[128];
  __shared__ int useConjS;
  __shared__ double normS;
  const int IL[10][3] = {{0,0,0},{1,1,0},{0,1,1},{1,0,1},{1,2,1},{0,2,2},{1,1,2},{1,3,2},{0,3,3},{1,2,3}};
  int k = blockIdx.x;
  int l1 = IL[k][0], l2 = IL[k][1], l3 = IL[k][2];
  int n1 = 2*l1+1, n2 = 2*l2+1, n3 = 2*l3+1;
  int nent = n1*n2*n3;
  int tid = threadIdx.x;
  double dcr=0, dci=0, dpr=0, dpi=0;
  if (tid < nent){
    int i = tid/(n2*n3), j = (tid/n3)%n2, kk = tid%n3;
    for (int a = 0; a < n1; ++a){
      for (int b = 0; b < n2; ++b){
        int m1 = a - l1, m2 = b - l2, m3 = m1 + m2;
        if (m3 < -l3 || m3 > l3) continue;
        int c = m3 + l3;
        double C = cgval(l1,l2,l3,m1,m2);
        if (C == 0.0) continue;
        cpx q1 = qval(l1,a,i), q2 = qval(l2,b,j), q3 = qval(l3,c,kk);
        cpx t = cmul(q1,q2);
        cpx q3c = { q3.re, -q3.im };
        cpx tc = cmul(t, q3c);
        cpx tp = cmul(t, q3);
        dcr += C*tc.re; dci += C*tc.im;
        dpr += C*tp.re; dpi += C*tp.im;
      }
    }
  }
  red[tid] = (tid < nent) ? fabs(dci) : 0.0;
  __syncthreads();
  if (tid == 0){
    double mx = 0.0;
    for (int t = 0; t < 128; ++t) if (red[t] > mx) mx = red[t];
    useConjS = (mx < 1e-9) ? 1 : 0;
  }
  __syncthreads();
  double re = useConjS ? dcr : dpr;
  red[tid] = (tid < nent) ? re*re : 0.0;
  __syncthreads();
  if (tid == 0){
    double s = 0.0;
    for (int t = 0; t < 128; ++t) s += red[t];
    normS = sqrt(s);
  }
  __syncthreads();
  if (tid < nent)
    ws[W3J_OFF + k*128 + tid] = (float)(re / normS * sqrt((double)(2*l3+1)));  // fold sqrt(2l3+1)
}

// ---------------------------------------------------------------- node transform
// h[n][512]: [0..128) = h0[v]; [128 + i*128 + v] = h1[n][v][i]
__launch_bounds__(256, 4)
__global__ void node_kernel(const float* __restrict__ nf, const float* __restrict__ W0,
                            const float* __restrict__ W1, float* __restrict__ ws){
  __shared__ float AtL[128*68];
  float* h = ws + H_OFF;
  int tid = threadIdx.x;
  int n0 = blockIdx.x * 64;
  const float rs = 0.08838834764831845f; // 1/sqrt(128)
  int mg = (tid & 15) * 4;
  int vg = (tid >> 4) * 8;
  for (int c = 0; c < 4; ++c){
    __syncthreads();
    for (int idx = tid; idx < 8192; idx += 256){
      int m = idx >> 7, u = idx & 127;
      int node = n0 + m;
      float v = 0.f;
      if (node < NNODES)
        v = (c == 0) ? nf[(size_t)node*512 + u] : nf[(size_t)node*512 + 128 + u*3 + (c-1)];
      AtL[u*68 + m] = v;
    }
    __syncthreads();
    const float* W = (c == 0) ? W0 : W1;
    float acc[8][4];
    #pragma unroll
    for (int a = 0; a < 8; ++a){ acc[a][0]=0.f; acc[a][1]=0.f; acc[a][2]=0.f; acc[a][3]=0.f; }
    for (int u = 0; u < 128; ++u){
      float4 am = *(const float4*)&AtL[u*68 + mg];
      const float* wr = W + u*128 + vg;
      float4 b0 = *(const float4*)wr;
      float4 b1 = *(const float4*)(wr + 4);
      float aa[4] = {am.x, am.y, am.z, am.w};
      float bb[8] = {b0.x,b0.y,b0.z,b0.w,b1.x,b1.y,b1.z,b1.w};
      #pragma unroll
      for (int a = 0; a < 8; ++a)
        #pragma unroll
        for (int e = 0; e < 4; ++e)
          acc[a][e] += bb[a]*aa[e];
    }
    #pragma unroll
    for (int e = 0; e < 4; ++e){
      int node = n0 + mg + e;
      if (node < NNODES){
        float4 s0 = {acc[0][e]*rs, acc[1][e]*rs, acc[2][e]*rs, acc[3][e]*rs};
        float4 s1 = {acc[4][e]*rs, acc[5][e]*rs, acc[6][e]*rs, acc[7][e]*rs};
        *(float4*)&h[(size_t)node*512 + c*128 + vg] = s0;
        *(float4*)&h[(size_t)node*512 + c*128 + vg + 4] = s1;
      }
    }
  }
}

// ---------------------------------------------------------------- edge kernel helpers
template<int KDIM>
__device__ __forceinline__ void mlp_layer(const float* __restrict__ Wg, const float* aL,
                                          float* oL, int tid, float scale){
  int eg = (tid & 15) * 4;
  int jg = (tid >> 4) * 4;
  float acc[4][4];
  #pragma unroll
  for (int a = 0; a < 4; ++a){ acc[a][0]=0.f; acc[a][1]=0.f; acc[a][2]=0.f; acc[a][3]=0.f; }
  #pragma unroll 4
  for (int i = 0; i < KDIM; ++i){
    float4 a4 = *(const float4*)&aL[i*68 + eg];
    float4 b4 = *(const float4*)&Wg[i*64 + jg];
    float aa[4] = {a4.x,a4.y,a4.z,a4.w};
    float bb[4] = {b4.x,b4.y,b4.z,b4.w};
    #pragma unroll
    for (int a = 0; a < 4; ++a)
      #pragma unroll
      for (int e = 0; e < 4; ++e)
        acc[a][e] += bb[a]*aa[e];
  }
  #pragma unroll
  for (int a = 0; a < 4; ++a){
    float4 st;
    float x0 = acc[a][0]*scale; st.x = x0/(1.f + expf(-x0));
    float x1 = acc[a][1]*scale; st.y = x1/(1.f + expf(-x1));
    float x2 = acc[a][2]*scale; st.z = x2/(1.f + expf(-x2));
    float x3 = acc[a][3]*scale; st.w = x3/(1.f + expf(-x3));
    *(float4*)&oL[(jg+a)*68 + eg] = st;
  }
}

__device__ __forceinline__ void gemm_w(const float* __restrict__ rw3, const float* r2Tl,
                                       float* wT, int k, int tid){
  int eg = (tid & 15) * 4;
  int ug = (tid >> 4) * 8;
  float acc[8][4];
  #pragma unroll
  for (int a = 0; a < 8; ++a){ acc[a][0]=0.f; acc[a][1]=0.f; acc[a][2]=0.f; acc[a][3]=0.f; }
  const float* bbase = rw3 + k*128 + ug;
  #pragma unroll 4
  for (int i = 0; i < 64; ++i){
    float4 a4 = *(const float4*)&r2Tl[i*68 + eg];
    const float* br = bbase + (size_t)i*1280;
    float4 b0 = *(const float4*)br;
    float4 b1 = *(const float4*)(br + 4);
    float aa[4] = {a4.x,a4.y,a4.z,a4.w};
    float bb[8] = {b0.x,b0.y,b0.z,b0.w,b1.x,b1.y,b1.z,b1.w};
    #pragma unroll
    for (int a = 0; a < 8; ++a)
      #pragma unroll
      for (int e = 0; e < 4; ++e)
        acc[a][e] += bb[a]*aa[e];
  }
  #pragma unroll
  for (int a = 0; a < 8; ++a){
    float4 st = { acc[a][0]*0.125f, acc[a][1]*0.125f, acc[a][2]*0.125f, acc[a][3]*0.125f };
    *(float4*)&wT[(ug+a)*68 + eg] = st;  // /8 for R_W3/sqrt(64)
  }
}

template<int L1,int L2,int L3,int SLOT,int SHOFF>
__device__ __forceinline__ void tp_step(const float* __restrict__ w3,
                                        const float* shL, const float* wT,
                                        const int* rLs, float* cat,
                                        int e, int u0,
                                        const float* h0r, const float (*h1r)[32]){
  constexpr int N2 = 2*L2+1, N3 = 2*L3+1;
  constexpr int N1 = 2*L1+1;
  float shv[N2];
  #pragma unroll
  for (int j = 0; j < N2; ++j) shv[j] = shL[(SHOFF+j)*64 + e];
  float cc[N1][N3];
  #pragma unroll
  for (int i = 0; i < N1; ++i)
    #pragma unroll
    for (int q = 0; q < N3; ++q){
      float s = 0.f;
      #pragma unroll
      for (int j = 0; j < N2; ++j)
        s += w3[(i*N2 + j)*N3 + q] * shv[j];
      cc[i][q] = s;
    }
  int recv = rLs[e];
  constexpr int GO = (L3==0) ? 0 : (L3==1) ? 256 : (L3==2) ? 1408 : 3328;
  float* base = cat + (size_t)recv*5120 + GO + SLOT*128*N3;
  #pragma unroll
  for (int jj = 0; jj < 32; ++jj){
    int u = u0 + jj;
    float wv = wT[u*68 + e];
    float* bp = base + u*N3;
    #pragma unroll
    for (int q = 0; q < N3; ++q){
      float v;
      if (L1 == 0) v = cc[0][q]*h0r[jj];
      else         v = cc[0][q]*h1r[0][jj] + cc[1][q]*h1r[1][jj] + cc[2][q]*h1r[2][jj];
      atomicAdd(bp + q, wv * v);
    }
  }
}

// ---------------------------------------------------------------- edge kernel
__launch_bounds__(256, 2)
__global__ void edge_kernel(const float* __restrict__ ea, const float* __restrict__ ef,
                            const int* __restrict__ ei,
                            const float* __restrict__ RW0, const float* __restrict__ RW1,
                            const float* __restrict__ RW2, const float* __restrict__ RW3,
                            float* ws){
  __shared__ float r2Tl[64*68];
  __shared__ float wT[128*68];
  __shared__ float shL[16*64];
  __shared__ int sL[64], rLs[64];
  const float* h = ws + H_OFF;
  float* cat = ws + CAT_OFF;
  const float* w3 = ws + W3J_OFF;
  int tid = threadIdx.x;
  int eb = blockIdx.x * 64;

  // stage edge_feats (transposed) into the shL area; senders/receivers
  float* efT = shL; // 8*68 = 544 <= 1024
  for (int idx = tid; idx < 512; idx += 256){
    int e = idx >> 3, i2 = idx & 7;
    efT[i2*68 + e] = ef[(size_t)(eb+e)*8 + i2];
  }
  if (tid < 64){ sL[tid] = ei[eb + tid]; rLs[tid] = ei[NEDGES + eb + tid]; }
  __syncthreads();

  // per-thread h registers (sender row), loaded once; overlaps with MLP compute
  int e = tid & 63, ub = tid >> 6;
  int u0 = ub * 32;
  int sN = sL[e];
  const float* hr = h + (size_t)sN*512;
  float h0r[32];
  float h1r[3][32];
  #pragma unroll
  for (int q = 0; q < 8; ++q){
    float4 t = *(const float4*)&hr[u0 + q*4];
    h0r[q*4+0]=t.x; h0r[q*4+1]=t.y; h0r[q*4+2]=t.z; h0r[q*4+3]=t.w;
  }
  #pragma unroll
  for (int i = 0; i < 3; ++i)
    #pragma unroll
    for (int q = 0; q < 8; ++q){
      float4 t = *(const float4*)&hr[128 + i*128 + u0 + q*4];
      h1r[i][q*4+0]=t.x; h1r[i][q*4+1]=t.y; h1r[i][q*4+2]=t.z; h1r[i][q*4+3]=t.w;
    }

  // radial MLP: ef -> 64 -> 64 -> 64 (silu each), tiles ping-pong through wT halves
  float* rA = wT;            // 64*68
  float* rB = wT + 64*68;    // 64*68
  mlp_layer<8 >(RW0, efT, rA, tid, 0.35355339059327373f);
  __syncthreads();
  mlp_layer<64>(RW1, rA, rB, tid, 0.125f);
  __syncthreads();
  mlp_layer<64>(RW2, rB, r2Tl, tid, 0.125f);
  __syncthreads();

  // stage sh (overwrites efT area, dead since layer 1)
  for (int idx = tid; idx < 1024; idx += 256){
    int ee = idx >> 4, jj = idx & 15;
    shL[jj*64 + ee] = ea[(size_t)(eb+ee)*16 + jj];
  }
  __syncthreads();

  // 10 instructions: GEMM slice of R_W3 -> wT, then tensor product + atomic scatter
  #define STEP(K, L1v, L2v, L3v, SLOTv, SHOFFv) \
    gemm_w(RW3, r2Tl, wT, K, tid); \
    __syncthreads(); \
    tp_step<L1v,L2v,L3v,SLOTv,SHOFFv>(w3 + K*128, shL, wT, rLs, cat, e, u0, h0r, h1r); \
    __syncthreads();

  STEP(0, 0,0,0, 0, 0)
  STEP(1, 1,1,0, 1, 1)
  STEP(2, 0,1,1, 0, 1)
  STEP(3, 1,0,1, 1, 0)
  STEP(4, 1,2,1, 2, 4)
  STEP(5, 0,2,2, 0, 4)
  STEP(6, 1,1,2, 1, 1)
  STEP(7, 1,3,2, 2, 9)
  STEP(8, 0,3,3, 0, 9)
  STEP(9, 1,2,3, 1, 4)
  #undef STEP
}

// ---------------------------------------------------------------- output kernel
template<int L>
__device__ __forceinline__ void out_group(const float* __restrict__ cat,
                                          const float* __restrict__ Wout,
                                          float* __restrict__ outp,
                                          float* AtL, float* Btl,
                                          int tid, int node0){
  constexpr int NI = 2*L+1;
  constexpr int UL = (L==0 || L==3) ? 256 : 384;
  constexpr int GO = (L==0)?0:(L==1)?256:(L==2)?1408:3328;
  constexpr int OO = (L==0)?0:(L==1)?1:(L==2)?4:9;
  const float scale = (L==0 || L==3) ? 0.00390625f : 0.0031894435433133252f; // 1/(sqrt(UL)*16)
  int vg = tid & 31, v0 = vg*4;
  int ng = tid >> 5, n0 = ng*2;
  float acc[2][4][NI];
  #pragma unroll
  for (int nn = 0; nn < 2; ++nn)
    #pragma unroll
    for (int vv = 0; vv < 4; ++vv)
      #pragma unroll
      for (int i = 0; i < NI; ++i) acc[nn][vv][i] = 0.f;
  for (int kt = 0; kt < UL/64; ++kt){
    __syncthreads();
    for (int idx = tid; idx < 16*64*NI; idx += 256){
      int n = idx / (64*NI);
      int rem = idx % (64*NI);
      AtL[n*(64*NI) + rem] = cat[(size_t)(node0+n)*5120 + GO + kt*(64*NI) + rem];
    }
    for (int idx = tid; idx < 2048; idx += 256){
      *(float4*)&Btl[idx*4] = *(const float4*)&Wout[(size_t)(kt*64)*128 + idx*4];
    }
    __syncthreads();
    for (int u = 0; u < 64; ++u){
      float4 b4 = *(const float4*)&Btl[u*128 + v0];
      float bb[4] = {b4.x,b4.y,b4.z,b4.w};
      #pragma unroll
      for (int nn = 0; nn < 2; ++nn){
        const float* ar = &AtL[((n0+nn)*64 + u)*NI];
        #pragma unroll
        for (int i = 0; i < NI; ++i){
          float a = ar[i];
          #pragma unroll
          for (int vv = 0; vv < 4; ++vv)
            acc[nn][vv][i] += a*bb[vv];
        }
      }
    }
  }
  #pragma unroll
  for (int nn = 0; nn < 2; ++nn)
    #pragma unroll
    for (int vv = 0; vv < 4; ++vv){
      float* op = outp + (size_t)(node0+n0+nn)*2048 + (v0+vv)*16 + OO;
      #pragma unroll
      for (int i = 0; i < NI; ++i)
        op[i] = acc[nn][vv][i]*scale;
    }
}

__launch_bounds__(256, 2)
__global__ void out_kernel(const float* __restrict__ ws,
                           const float* __restrict__ Wo0, const float* __restrict__ Wo1,
                           const float* __restrict__ Wo2, const float* __restrict__ Wo3,
                           float* __restrict__ outp){
  __shared__ float AtL[16*64*7];
  __shared__ float Btl[64*128];
  const float* cat = ws + CAT_OFF;
  int node0 = blockIdx.x * 16;
  int tid = threadIdx.x;
  out_group<0>(cat, Wo0, outp, AtL, Btl, tid, node0);
  out_group<1>(cat, Wo1, outp, AtL, Btl, tid, node0);
  out_group<2>(cat, Wo2, outp, AtL, Btl, tid, node0);
  out_group<3>(cat, Wo3, outp, AtL, Btl, tid, node0);
}

// ---------------------------------------------------------------- launch
extern "C" void kernel_launch(void* const* d_in, const int* in_sizes, int n_in,
                              void* d_out, int out_size, void* d_ws, size_t ws_size,
                              hipStream_t stream){
  const float* nf  = (const float*)d_in[0];
  const float* ea  = (const float*)d_in[2];
  const float* ef  = (const float*)d_in[3];
  const int*   ei  = (const int*)d_in[4];
  const float* W0  = (const float*)d_in[5];
  const float* W1  = (const float*)d_in[6];
  const float* RW0 = (const float*)d_in[7];
  const float* RW1 = (const float*)d_in[8];
  const float* RW2 = (const float*)d_in[9];
  const float* RW3 = (const float*)d_in[10];
  const float* Wo0 = (const float*)d_in[11];
  const float* Wo1 = (const float*)d_in[12];
  const float* Wo2 = (const float*)d_in[13];
  const float* Wo3 = (const float*)d_in[14];
  float* ws   = (float*)d_ws;
  float* outp = (float*)d_out;

  hipMemsetAsync(ws + CAT_OFF, 0, (size_t)NNODES*5120*sizeof(float), stream);
  w3j_kernel<<<10, 128, 0, stream>>>(ws);
  node_kernel<<<157, 256, 0, stream>>>(nf, W0, W1, ws);
  edge_kernel<<<2048, 256, 0, stream>>>(ea, ef, ei, RW0, RW1, RW2, RW3, ws);
  out_kernel<<<625, 256, 0, stream>>>(ws, Wo0, Wo1, Wo2, Wo3, outp);
}

// Round 2
// 3509.703 us; speedup vs baseline: 11.3224x; 11.3224x over previous
//
#include <hip/hip_runtime.h>
#include <math.h>

#define NNODES 10000
#define NEDGES 131072

// ws layout (word offsets, 4B words)
#define W3J_OFF 0                          // 1280 floats
#define H_OFF   1280                       // NNODES*512 floats
#define R2_OFF  (1280 + NNODES*512)        // NEDGES*64 floats
#define CSR_W   (R2_OFF + NEDGES*64)
#define CNT_W   CSR_W                      // 10000 ints
#define CUR_W   (CSR_W + NNODES)           // 10000 ints
#define OFF_W   (CSR_W + 2*NNODES)         // 10001 ints
#define ELIST_W (CSR_W + 2*NNODES + NNODES + 1)  // NEDGES ints

// instruction tables (compile-time)
constexpr int cL1[10]  = {0,1,0,1,1,0,1,1,0,1};
constexpr int cL2[10]  = {0,1,1,0,2,2,1,3,3,2};
constexpr int cN3[10]  = {1,1,3,3,3,5,5,5,7,7};
constexpr int cSHO[10] = {0,1,1,0,4,4,1,9,9,4};
constexpr int cCCO[11] = {0,1,4,7,16,25,30,45,60,67,88};
constexpr int cCATO[10]= {0,128,256,640,1024,1408,2048,2688,3328,4224};

// ---------------------------------------------------------------- w3j kernel
struct cpx { double re, im; };
__device__ inline cpx cmul(cpx a, cpx b){ return {a.re*b.re - a.im*b.im, a.re*b.im + a.im*b.re}; }

__device__ double dfact(int n){ double r = 1.0; for (int i = 2; i <= n; ++i) r *= (double)i; return r; }

__device__ double cgval(int j1,int j2,int j3,int m1,int m2){
  int m3 = m1 + m2;
  if (m3 > j3 || m3 < -j3) return 0.0;
  double pref = (double)(2*j3+1) * dfact(j3+j1-j2)*dfact(j3-j1+j2)*dfact(j1+j2-j3)/dfact(j1+j2+j3+1);
  pref *= dfact(j3+m3)*dfact(j3-m3)*dfact(j1-m1)*dfact(j1+m1)*dfact(j2-m2)*dfact(j2+m2);
  int k0 = 0; if (-(j3-j2+m1) > k0) k0 = -(j3-j2+m1); if (-(j3-j1-m2) > k0) k0 = -(j3-j1-m2);
  int k1 = j1+j2-j3; if (j1-m1 < k1) k1 = j1-m1; if (j2+m2 < k1) k1 = j2+m2;
  double s = 0.0;
  for (int k = k0; k <= k1; ++k){
    double d = dfact(k)*dfact(j1+j2-j3-k)*dfact(j1-m1-k)*dfact(j2+m2-k)*dfact(j3-j2+m1+k)*dfact(j3-j1-m2+k);
    s += ((k & 1) ? -1.0 : 1.0) / d;
  }
  return sqrt(pref) * s;
}

__device__ cpx qval(int l, int a, int col){
  int m = a - l;
  const double is2 = 0.70710678118654752440;
  double re = 0.0, im = 0.0;
  if (m < 0){
    if (col == l - m) re = is2;
    else if (col == l + m) im = -is2;
  } else if (m == 0){
    if (col == l) re = 1.0;
  } else {
    double sgn = (m & 1) ? -1.0 : 1.0;
    if (col == l + m) re = sgn * is2;
    else if (col == l - m) im = sgn * is2;
  }
  double pr, pi;  // (-i)^l
  switch (l & 3){ case 0: pr=1; pi=0; break; case 1: pr=0; pi=-1; break; case 2: pr=-1; pi=0; break; default: pr=0; pi=1; }
  return { re*pr - im*pi, re*pi + im*pr };
}

__global__ void w3j_kernel(float* ws){
  __shared__ double red[128];
  __shared__ int useConjS;
  __shared__ double normS;
  const int IL[10][3] = {{0,0,0},{1,1,0},{0,1,1},{1,0,1},{1,2,1},{0,2,2},{1,1,2},{1,3,2},{0,3,3},{1,2,3}};
  int k = blockIdx.x;
  int l1 = IL[k][0], l2 = IL[k][1], l3 = IL[k][2];
  int n1 = 2*l1+1, n2 = 2*l2+1, n3 = 2*l3+1;
  int nent = n1*n2*n3;
  int tid = threadIdx.x;
  double dcr=0, dci=0, dpr=0, dpi=0;
  if (tid < nent){
    int i = tid/(n2*n3), j = (tid/n3)%n2, kk = tid%n3;
    for (int a = 0; a < n1; ++a){
      for (int b = 0; b < n2; ++b){
        int m1 = a - l1, m2 = b - l2, m3 = m1 + m2;
        if (m3 < -l3 || m3 > l3) continue;
        int c = m3 + l3;
        double C = cgval(l1,l2,l3,m1,m2);
        if (C == 0.0) continue;
        cpx q1 = qval(l1,a,i), q2 = qval(l2,b,j), q3 = qval(l3,c,kk);
        cpx t = cmul(q1,q2);
        cpx q3c = { q3.re, -q3.im };
        cpx tc = cmul(t, q3c);
        cpx tp = cmul(t, q3);
        dcr += C*tc.re; dci += C*tc.im;
        dpr += C*tp.re; dpi += C*tp.im;
      }
    }
  }
  red[tid] = (tid < nent) ? fabs(dci) : 0.0;
  __syncthreads();
  if (tid == 0){
    double mx = 0.0;
    for (int t = 0; t < 128; ++t) if (red[t] > mx) mx = red[t];
    useConjS = (mx < 1e-9) ? 1 : 0;
  }
  __syncthreads();
  double re = useConjS ? dcr : dpr;
  red[tid] = (tid < nent) ? re*re : 0.0;
  __syncthreads();
  if (tid == 0){
    double s = 0.0;
    for (int t = 0; t < 128; ++t) s += red[t];
    normS = sqrt(s);
  }
  __syncthreads();
  if (tid < nent)
    ws[W3J_OFF + k*128 + tid] = (float)(re / normS * sqrt((double)(2*l3+1)));  // fold sqrt(2l3+1)
}

// ---------------------------------------------------------------- node transform
// h[n][512]: [0..128) = h0[v]; [128 + i*128 + v] = h1[n][v][i]
__launch_bounds__(256, 4)
__global__ void node_kernel(const float* __restrict__ nf, const float* __restrict__ W0,
                            const float* __restrict__ W1, float* __restrict__ ws){
  __shared__ float AtL[128*68];
  float* h = ws + H_OFF;
  int tid = threadIdx.x;
  int n0 = blockIdx.x * 64;
  const float rs = 0.08838834764831845f; // 1/sqrt(128)
  int mg = (tid & 15) * 4;
  int vg = (tid >> 4) * 8;
  for (int c = 0; c < 4; ++c){
    __syncthreads();
    for (int idx = tid; idx < 8192; idx += 256){
      int m = idx >> 7, u = idx & 127;
      int node = n0 + m;
      float v = 0.f;
      if (node < NNODES)
        v = (c == 0) ? nf[(size_t)node*512 + u] : nf[(size_t)node*512 + 128 + u*3 + (c-1)];
      AtL[u*68 + m] = v;
    }
    __syncthreads();
    const float* W = (c == 0) ? W0 : W1;
    float acc[8][4];
    #pragma unroll
    for (int a = 0; a < 8; ++a){ acc[a][0]=0.f; acc[a][1]=0.f; acc[a][2]=0.f; acc[a][3]=0.f; }
    for (int u = 0; u < 128; ++u){
      float4 am = *(const float4*)&AtL[u*68 + mg];
      const float* wr = W + u*128 + vg;
      float4 b0 = *(const float4*)wr;
      float4 b1 = *(const float4*)(wr + 4);
      float aa[4] = {am.x, am.y, am.z, am.w};
      float bb[8] = {b0.x,b0.y,b0.z,b0.w,b1.x,b1.y,b1.z,b1.w};
      #pragma unroll
      for (int a = 0; a < 8; ++a)
        #pragma unroll
        for (int e = 0; e < 4; ++e)
          acc[a][e] += bb[a]*aa[e];
    }
    #pragma unroll
    for (int e = 0; e < 4; ++e){
      int node = n0 + mg + e;
      if (node < NNODES){
        float4 s0 = {acc[0][e]*rs, acc[1][e]*rs, acc[2][e]*rs, acc[3][e]*rs};
        float4 s1 = {acc[4][e]*rs, acc[5][e]*rs, acc[6][e]*rs, acc[7][e]*rs};
        *(float4*)&h[(size_t)node*512 + c*128 + vg] = s0;
        *(float4*)&h[(size_t)node*512 + c*128 + vg + 4] = s1;
      }
    }
  }
}

// ---------------------------------------------------------------- radial MLP (r2)
template<int KDIM>
__device__ __forceinline__ void mlp_layer(const float* __restrict__ Wg, const float* aL,
                                          float* oL, int tid, float scale){
  int eg = (tid & 15) * 4;
  int jg = (tid >> 4) * 4;
  float acc[4][4];
  #pragma unroll
  for (int a = 0; a < 4; ++a){ acc[a][0]=0.f; acc[a][1]=0.f; acc[a][2]=0.f; acc[a][3]=0.f; }
  #pragma unroll 4
  for (int i = 0; i < KDIM; ++i){
    float4 a4 = *(const float4*)&aL[i*68 + eg];
    float4 b4 = *(const float4*)&Wg[i*64 + jg];
    float aa[4] = {a4.x,a4.y,a4.z,a4.w};
    float bb[4] = {b4.x,b4.y,b4.z,b4.w};
    #pragma unroll
    for (int a = 0; a < 4; ++a)
      #pragma unroll
      for (int e = 0; e < 4; ++e)
        acc[a][e] += bb[a]*aa[e];
  }
  #pragma unroll
  for (int a = 0; a < 4; ++a){
    float4 st;
    float x0 = acc[a][0]*scale; st.x = x0/(1.f + expf(-x0));
    float x1 = acc[a][1]*scale; st.y = x1/(1.f + expf(-x1));
    float x2 = acc[a][2]*scale; st.z = x2/(1.f + expf(-x2));
    float x3 = acc[a][3]*scale; st.w = x3/(1.f + expf(-x3));
    *(float4*)&oL[(jg+a)*68 + eg] = st;
  }
}

__launch_bounds__(256)
__global__ void r2_kernel(const float* __restrict__ ef,
                          const float* __restrict__ RW0, const float* __restrict__ RW1,
                          const float* __restrict__ RW2, float* __restrict__ wsf){
  __shared__ float bufA[64*68];
  __shared__ float bufB[64*68];
  __shared__ float r2T[64*68];
  float* R2 = wsf + R2_OFF;
  int tid = threadIdx.x;
  int eb = blockIdx.x * 64;
  float* efT = r2T;  // 8*68 fits; dead after layer 1
  for (int idx = tid; idx < 512; idx += 256){
    int e = idx >> 3, i2 = idx & 7;
    efT[i2*68 + e] = ef[(size_t)(eb+e)*8 + i2];
  }
  __syncthreads();
  mlp_layer<8 >(RW0, efT, bufA, tid, 0.35355339059327373f);
  __syncthreads();
  mlp_layer<64>(RW1, bufA, bufB, tid, 0.125f);
  __syncthreads();
  mlp_layer<64>(RW2, bufB, r2T, tid, 0.125f);
  __syncthreads();
  for (int idx = tid; idx < 4096; idx += 256){
    int e = idx >> 6, i = idx & 63;
    R2[((size_t)(eb+e) << 6) + i] = r2T[i*68 + e];
  }
}

// ---------------------------------------------------------------- CSR build
__global__ void hist_kernel(const int* __restrict__ ei, int* __restrict__ cnt){
  int e = blockIdx.x*256 + threadIdx.x;
  if (e < NEDGES) atomicAdd(&cnt[ei[NEDGES + e]], 1);
}

__global__ void scan_kernel(const int* __restrict__ cnt, int* __restrict__ off){
  __shared__ int part[256];
  __shared__ int partp[256];
  int t = threadIdx.x;
  const int S = 40;  // 256*40 >= 10001
  int s = 0;
  for (int j = 0; j < S; ++j){ int idx = t*S + j; if (idx < NNODES) s += cnt[idx]; }
  part[t] = s;
  __syncthreads();
  if (t == 0){ int run = 0; for (int i = 0; i < 256; ++i){ partp[i] = run; run += part[i]; } }
  __syncthreads();
  int run = partp[t];
  for (int j = 0; j < S; ++j){
    int idx = t*S + j;
    if (idx <= NNODES){
      off[idx] = run;
      if (idx < NNODES) run += cnt[idx];
    }
  }
}

__global__ void fill_kernel(const int* __restrict__ ei, const int* __restrict__ off,
                            int* __restrict__ cur, int* __restrict__ elist){
  int e = blockIdx.x*256 + threadIdx.x;
  if (e < NEDGES){
    int r = ei[NEDGES + e];
    int p = off[r] + atomicAdd(&cur[r], 1);
    elist[p] = e;
  }
}

// ---------------------------------------------------------------- gather helpers
__device__ __forceinline__ float cc_compute(int r, const float* w3L, const float* she){
  float v = 0.f;
  #pragma unroll
  for (int in = 0; in < 10; ++in){
    if (r >= cCCO[in] && r < cCCO[in+1]){
      int rr = r - cCCO[in];
      const int N3v = cN3[in];
      const int N2v = 2*cL2[in] + 1;
      int i = rr / N3v;
      int q = rr - i*N3v;
      float s = 0.f;
      for (int j = 0; j < N2v; ++j)
        s += w3L[in*128 + (i*N2v + j)*N3v + q] * she[cSHO[in] + j];
      v = s;
    }
  }
  return v;
}

template<int IN>
__device__ __forceinline__ void tp_one(const float* __restrict__ cce, const float* __restrict__ he,
                                       int u, float wv, float* accm){
  constexpr int N3v = cN3[IN];
  #pragma unroll
  for (int q = 0; q < N3v; ++q){
    float val;
    if constexpr (cL1[IN] == 0)
      val = cce[q] * he[u];
    else
      val = cce[q]*he[128+u] + cce[N3v+q]*he[256+u] + cce[2*N3v+q]*he[384+u];
    accm[q] += wv * val;
  }
}

template<int IN>
__device__ __forceinline__ void st_cat(float* catL, int u, const float* accm){
  constexpr int N3v = cN3[IN];
  float* p = catL + cCATO[IN] + u*N3v;
  #pragma unroll
  for (int q = 0; q < N3v; ++q) p[q] = accm[q];
}

template<int L>
__device__ __forceinline__ void out_g(const float* catL, const float* __restrict__ Wo,
                                      float* redL, float* __restrict__ outp,
                                      int n, int v, int half){
  constexpr int NI = 2*L + 1;
  constexpr int UL = (L==0 || L==3) ? 256 : 384;
  constexpr int GOv = (L==0) ? 0 : (L==1) ? 256 : (L==2) ? 1408 : 3328;
  constexpr int OOv = (L==0) ? 0 : (L==1) ? 1 : (L==2) ? 4 : 9;
  const float scale = (L==0 || L==3) ? 0.00390625f : 0.0031894435433133252f; // 1/(sqrt(UL)*16)
  float o[NI];
  #pragma unroll
  for (int i = 0; i < NI; ++i) o[i] = 0.f;
  int ul0 = half * (UL/2);
  for (int ul = ul0; ul < ul0 + UL/2; ++ul){
    float wv = Wo[(size_t)ul*128 + v];
    const float* a = catL + GOv + ul*NI;
    #pragma unroll
    for (int i = 0; i < NI; ++i) o[i] += a[i]*wv;
  }
  if (half == 1){
    #pragma unroll
    for (int i = 0; i < NI; ++i) redL[v*NI + i] = o[i];
  }
  __syncthreads();
  if (half == 0){
    float* op = outp + (size_t)n*2048 + v*16 + OOv;
    #pragma unroll
    for (int i = 0; i < NI; ++i) op[i] = (o[i] + redL[v*NI + i]) * scale;
  }
  __syncthreads();
}

// ---------------------------------------------------------------- gather kernel
// one block per receiver node; cat row accumulated in registers; output linear fused
__launch_bounds__(256)
__global__ void gather_kernel(const float* __restrict__ ea, const int* __restrict__ ei,
                              const float* __restrict__ RW3,
                              const float* __restrict__ Wo0, const float* __restrict__ Wo1,
                              const float* __restrict__ Wo2, const float* __restrict__ Wo3,
                              const float* __restrict__ wsf,
                              const int* __restrict__ off, const int* __restrict__ elist,
                              float* __restrict__ outp){
  __shared__ float w3L[1280];
  __shared__ float catL[5120];
  __shared__ float hL[8*512];
  __shared__ float r2L[8*64];
  __shared__ float shL[8*16];
  __shared__ float ccL[8*88];
  __shared__ int   idsL[512];
  __shared__ int   idsC[8];
  __shared__ int   sC[8];
  const float* h  = wsf + H_OFF;
  const float* R2 = wsf + R2_OFF;
  int nblk = blockIdx.x, tid = threadIdx.x;
  for (int idx = tid; idx < 1280; idx += 256) w3L[idx] = wsf[W3J_OFF + idx];
  int beg = off[nblk], end = off[nblk+1];
  int deg = end - beg;
  int degc = deg < 512 ? deg : 512;
  for (int idx = tid; idx < degc; idx += 256) idsL[idx] = elist[beg + idx];
  __syncthreads();
  // sort edge ids (deterministic accumulation order); odd-even transposition
  for (int p = 0; p < degc; ++p){
    int i1 = 2*tid + (p & 1);
    if (i1 + 1 < degc){
      int a = idsL[i1], b = idsL[i1+1];
      if (b < a){ idsL[i1] = b; idsL[i1+1] = a; }
    }
    __syncthreads();
  }
  int u = tid & 127;
  int i0 = tid >> 7;           // 0 -> even instrs, 1 -> odd instrs (wave-uniform)
  float acc[5][7];
  #pragma unroll
  for (int m = 0; m < 5; ++m)
    #pragma unroll
    for (int q = 0; q < 7; ++q) acc[m][q] = 0.f;

  for (int base = 0; base < deg; base += 8){
    int eN = deg - base; if (eN > 8) eN = 8;
    __syncthreads();  // guard LDS reuse vs previous chunk's reads
    if (tid < 8){
      int id = 0;
      int k = base + tid;
      if (tid < eN) id = (k < degc) ? idsL[k] : elist[beg + k];
      idsC[tid] = id;
      sC[tid]   = ei[id];       // sender
    }
    __syncthreads();
    for (int idx = tid; idx < (eN << 9); idx += 256){
      int e = idx >> 9, j = idx & 511;
      hL[idx] = h[((size_t)sC[e] << 9) + j];
    }
    for (int idx = tid; idx < (eN << 6); idx += 256){
      int e = idx >> 6, i = idx & 63;
      r2L[idx] = R2[((size_t)idsC[e] << 6) + i];
    }
    for (int idx = tid; idx < (eN << 4); idx += 256){
      int e = idx >> 4, j = idx & 15;
      shL[idx] = ea[((size_t)idsC[e] << 4) + j];
    }
    __syncthreads();
    for (int idx = tid; idx < eN*88; idx += 256){
      int e = idx / 88, r = idx - e*88;
      ccL[idx] = cc_compute(r, w3L, shL + e*16);
    }
    // w-GEMM: w[m][e] = (r2[e] . RW3[:, c0+256m]) / 8
    float w[5][8];
    #pragma unroll
    for (int m = 0; m < 5; ++m)
      #pragma unroll
      for (int e = 0; e < 8; ++e) w[m][e] = 0.f;
    const float* rwp = RW3 + tid;
    for (int i = 0; i < 64; ++i){
      float bm[5];
      #pragma unroll
      for (int m = 0; m < 5; ++m) bm[m] = rwp[(size_t)i*1280 + 256*m];
      #pragma unroll
      for (int e = 0; e < 8; ++e){
        float rv = r2L[(e << 6) + i];
        #pragma unroll
        for (int m = 0; m < 5; ++m) w[m][e] += bm[m]*rv;
      }
    }
    #pragma unroll
    for (int m = 0; m < 5; ++m)
      #pragma unroll
      for (int e = 0; e < 8; ++e) w[m][e] *= 0.125f;
    __syncthreads();  // ccL ready
    #pragma unroll
    for (int e = 0; e < 8; ++e){
      if (e < eN){
        const float* cce = ccL + e*88;
        const float* he  = hL + (e << 9);
        if (i0 == 0){
          tp_one<0>(cce + cCCO[0], he, u, w[0][e], acc[0]);
          tp_one<2>(cce + cCCO[2], he, u, w[1][e], acc[1]);
          tp_one<4>(cce + cCCO[4], he, u, w[2][e], acc[2]);
          tp_one<6>(cce + cCCO[6], he, u, w[3][e], acc[3]);
          tp_one<8>(cce + cCCO[8], he, u, w[4][e], acc[4]);
        } else {
          tp_one<1>(cce + cCCO[1], he, u, w[0][e], acc[0]);
          tp_one<3>(cce + cCCO[3], he, u, w[1][e], acc[1]);
          tp_one<5>(cce + cCCO[5], he, u, w[2][e], acc[2]);
          tp_one<7>(cce + cCCO[7], he, u, w[3][e], acc[3]);
          tp_one<9>(cce + cCCO[9], he, u, w[4][e], acc[4]);
        }
      }
    }
  }
  __syncthreads();
  if (i0 == 0){
    st_cat<0>(catL, u, acc[0]);
    st_cat<2>(catL, u, acc[1]);
    st_cat<4>(catL, u, acc[2]);
    st_cat<6>(catL, u, acc[3]);
    st_cat<8>(catL, u, acc[4]);
  } else {
    st_cat<1>(catL, u, acc[0]);
    st_cat<3>(catL, u, acc[1]);
    st_cat<5>(catL, u, acc[2]);
    st_cat<7>(catL, u, acc[3]);
    st_cat<9>(catL, u, acc[4]);
  }
  __syncthreads();
  // fused output linear; redL aliases hL (dead)
  float* redL = hL;
  out_g<0>(catL, Wo0, redL, outp, nblk, u, i0);
  out_g<1>(catL, Wo1, redL, outp, nblk, u, i0);
  out_g<2>(catL, Wo2, redL, outp, nblk, u, i0);
  out_g<3>(catL, Wo3, redL, outp, nblk, u, i0);
}

// ---------------------------------------------------------------- launch
extern "C" void kernel_launch(void* const* d_in, const int* in_sizes, int n_in,
                              void* d_out, int out_size, void* d_ws, size_t ws_size,
                              hipStream_t stream){
  const float* nf  = (const float*)d_in[0];
  const float* ea  = (const float*)d_in[2];
  const float* ef  = (const float*)d_in[3];
  const int*   ei  = (const int*)d_in[4];
  const float* W0  = (const float*)d_in[5];
  const float* W1  = (const float*)d_in[6];
  const float* RW0 = (const float*)d_in[7];
  const float* RW1 = (const float*)d_in[8];
  const float* RW2 = (const float*)d_in[9];
  const float* RW3 = (const float*)d_in[10];
  const float* Wo0 = (const float*)d_in[11];
  const float* Wo1 = (const float*)d_in[12];
  const float* Wo2 = (const float*)d_in[13];
  const float* Wo3 = (const float*)d_in[14];
  float* wsf  = (float*)d_ws;
  int*   wsi  = (int*)d_ws;
  float* outp = (float*)d_out;

  hipMemsetAsync(wsi + CNT_W, 0, 2*NNODES*sizeof(int), stream);  // cnt + cur
  w3j_kernel<<<10, 128, 0, stream>>>(wsf);
  node_kernel<<<157, 256, 0, stream>>>(nf, W0, W1, wsf);
  r2_kernel<<<2048, 256, 0, stream>>>(ef, RW0, RW1, RW2, wsf);
  hist_kernel<<<512, 256, 0, stream>>>(ei, wsi + CNT_W);
  scan_kernel<<<1, 256, 0, stream>>>(wsi + CNT_W, wsi + OFF_W);
  fill_kernel<<<512, 256, 0, stream>>>(ei, wsi + OFF_W, wsi + CUR_W, wsi + ELIST_W);
  gather_kernel<<<NNODES, 256, 0, stream>>>(ea, ei, RW3, Wo0, Wo1, Wo2, Wo3,
                                            wsf, wsi + OFF_W, wsi + ELIST_W, outp);
}

// Round 3
// 2158.710 us; speedup vs baseline: 18.4083x; 1.6258x over previous
//
#include <hip/hip_runtime.h>
#include <math.h>

#define NNODES 10000
#define NEDGES 131072
#define CHUNK 16

// ws layout (word offsets, 4B words)
#define W3J_OFF 0                          // 1280 floats
#define H_OFF   1280                       // NNODES*512 floats
#define R2_OFF  (1280 + NNODES*512)        // NEDGES*64 floats
#define CSR_W   (R2_OFF + NEDGES*64)
#define CNT_W   CSR_W                      // 10000 ints
#define CUR_W   (CSR_W + NNODES)           // 10000 ints
#define OFF_W   (CSR_W + 2*NNODES)         // 10001 ints
#define ELIST_W (CSR_W + 2*NNODES + NNODES + 1)  // NEDGES ints

// instruction tables (compile-time)
constexpr int cL1[10]  = {0,1,0,1,1,0,1,1,0,1};
constexpr int cL2[10]  = {0,1,1,0,2,2,1,3,3,2};
constexpr int cN3[10]  = {1,1,3,3,3,5,5,5,7,7};
constexpr int cSHO[10] = {0,1,1,0,4,4,1,9,9,4};
constexpr int cCCO[11] = {0,1,4,7,16,25,30,45,60,67,88};
constexpr int cCATO[10]= {0,128,256,640,1024,1408,2048,2688,3328,4224};

// ---------------------------------------------------------------- w3j kernel
struct cpx { double re, im; };
__device__ inline cpx cmul(cpx a, cpx b){ return {a.re*b.re - a.im*b.im, a.re*b.im + a.im*b.re}; }

__device__ double dfact(int n){ double r = 1.0; for (int i = 2; i <= n; ++i) r *= (double)i; return r; }

__device__ double cgval(int j1,int j2,int j3,int m1,int m2){
  int m3 = m1 + m2;
  if (m3 > j3 || m3 < -j3) return 0.0;
  double pref = (double)(2*j3+1) * dfact(j3+j1-j2)*dfact(j3-j1+j2)*dfact(j1+j2-j3)/dfact(j1+j2+j3+1);
  pref *= dfact(j3+m3)*dfact(j3-m3)*dfact(j1-m1)*dfact(j1+m1)*dfact(j2-m2)*dfact(j2+m2);
  int k0 = 0; if (-(j3-j2+m1) > k0) k0 = -(j3-j2+m1); if (-(j3-j1-m2) > k0) k0 = -(j3-j1-m2);
  int k1 = j1+j2-j3; if (j1-m1 < k1) k1 = j1-m1; if (j2+m2 < k1) k1 = j2+m2;
  double s = 0.0;
  for (int k = k0; k <= k1; ++k){
    double d = dfact(k)*dfact(j1+j2-j3-k)*dfact(j1-m1-k)*dfact(j2+m2-k)*dfact(j3-j2+m1+k)*dfact(j3-j1-m2+k);
    s += ((k & 1) ? -1.0 : 1.0) / d;
  }
  return sqrt(pref) * s;
}

__device__ cpx qval(int l, int a, int col){
  int m = a - l;
  const double is2 = 0.70710678118654752440;
  double re = 0.0, im = 0.0;
  if (m < 0){
    if (col == l - m) re = is2;
    else if (col == l + m) im = -is2;
  } else if (m == 0){
    if (col == l) re = 1.0;
  } else {
    double sgn = (m & 1) ? -1.0 : 1.0;
    if (col == l + m) re = sgn * is2;
    else if (col == l - m) im = sgn * is2;
  }
  double pr, pi;  // (-i)^l
  switch (l & 3){ case 0: pr=1; pi=0; break; case 1: pr=0; pi=-1; break; case 2: pr=-1; pi=0; break; default: pr=0; pi=1; }
  return { re*pr - im*pi, re*pi + im*pr };
}

__global__ void w3j_kernel(float* ws){
  __shared__ double red[128];
  __shared__ int useConjS;
  __shared__ double normS;
  const int IL[10][3] = {{0,0,0},{1,1,0},{0,1,1},{1,0,1},{1,2,1},{0,2,2},{1,1,2},{1,3,2},{0,3,3},{1,2,3}};
  int k = blockIdx.x;
  int l1 = IL[k][0], l2 = IL[k][1], l3 = IL[k][2];
  int n1 = 2*l1+1, n2 = 2*l2+1, n3 = 2*l3+1;
  int nent = n1*n2*n3;
  int tid = threadIdx.x;
  double dcr=0, dci=0, dpr=0, dpi=0;
  if (tid < nent){
    int i = tid/(n2*n3), j = (tid/n3)%n2, kk = tid%n3;
    for (int a = 0; a < n1; ++a){
      for (int b = 0; b < n2; ++b){
        int m1 = a - l1, m2 = b - l2, m3 = m1 + m2;
        if (m3 < -l3 || m3 > l3) continue;
        int c = m3 + l3;
        double C = cgval(l1,l2,l3,m1,m2);
        if (C == 0.0) continue;
        cpx q1 = qval(l1,a,i), q2 = qval(l2,b,j), q3 = qval(l3,c,kk);
        cpx t = cmul(q1,q2);
        cpx q3c = { q3.re, -q3.im };
        cpx tc = cmul(t, q3c);
        cpx tp = cmul(t, q3);
        dcr += C*tc.re; dci += C*tc.im;
        dpr += C*tp.re; dpi += C*tp.im;
      }
    }
  }
  red[tid] = (tid < nent) ? fabs(dci) : 0.0;
  __syncthreads();
  if (tid == 0){
    double mx = 0.0;
    for (int t = 0; t < 128; ++t) if (red[t] > mx) mx = red[t];
    useConjS = (mx < 1e-9) ? 1 : 0;
  }
  __syncthreads();
  double re = useConjS ? dcr : dpr;
  red[tid] = (tid < nent) ? re*re : 0.0;
  __syncthreads();
  if (tid == 0){
    double s = 0.0;
    for (int t = 0; t < 128; ++t) s += red[t];
    normS = sqrt(s);
  }
  __syncthreads();
  if (tid < nent)
    ws[W3J_OFF + k*128 + tid] = (float)(re / normS * sqrt((double)(2*l3+1)));  // fold sqrt(2l3+1)
}

// ---------------------------------------------------------------- node transform
// h[n][512]: [0..128) = h0[v]; [128 + i*128 + v] = h1[n][v][i]
__launch_bounds__(256, 4)
__global__ void node_kernel(const float* __restrict__ nf, const float* __restrict__ W0,
                            const float* __restrict__ W1, float* __restrict__ ws){
  __shared__ float AtL[128*68];
  float* h = ws + H_OFF;
  int tid = threadIdx.x;
  int n0 = blockIdx.x * 64;
  const float rs = 0.08838834764831845f; // 1/sqrt(128)
  int mg = (tid & 15) * 4;
  int vg = (tid >> 4) * 8;
  for (int c = 0; c < 4; ++c){
    __syncthreads();
    for (int idx = tid; idx < 8192; idx += 256){
      int m = idx >> 7, u = idx & 127;
      int node = n0 + m;
      float v = 0.f;
      if (node < NNODES)
        v = (c == 0) ? nf[(size_t)node*512 + u] : nf[(size_t)node*512 + 128 + u*3 + (c-1)];
      AtL[u*68 + m] = v;
    }
    __syncthreads();
    const float* W = (c == 0) ? W0 : W1;
    float acc[8][4];
    #pragma unroll
    for (int a = 0; a < 8; ++a){ acc[a][0]=0.f; acc[a][1]=0.f; acc[a][2]=0.f; acc[a][3]=0.f; }
    for (int u = 0; u < 128; ++u){
      float4 am = *(const float4*)&AtL[u*68 + mg];
      const float* wr = W + u*128 + vg;
      float4 b0 = *(const float4*)wr;
      float4 b1 = *(const float4*)(wr + 4);
      float aa[4] = {am.x, am.y, am.z, am.w};
      float bb[8] = {b0.x,b0.y,b0.z,b0.w,b1.x,b1.y,b1.z,b1.w};
      #pragma unroll
      for (int a = 0; a < 8; ++a)
        #pragma unroll
        for (int e = 0; e < 4; ++e)
          acc[a][e] += bb[a]*aa[e];
    }
    #pragma unroll
    for (int e = 0; e < 4; ++e){
      int node = n0 + mg + e;
      if (node < NNODES){
        float4 s0 = {acc[0][e]*rs, acc[1][e]*rs, acc[2][e]*rs, acc[3][e]*rs};
        float4 s1 = {acc[4][e]*rs, acc[5][e]*rs, acc[6][e]*rs, acc[7][e]*rs};
        *(float4*)&h[(size_t)node*512 + c*128 + vg] = s0;
        *(float4*)&h[(size_t)node*512 + c*128 + vg + 4] = s1;
      }
    }
  }
}

// ---------------------------------------------------------------- radial MLP (r2)
template<int KDIM>
__device__ __forceinline__ void mlp_layer(const float* __restrict__ Wg, const float* aL,
                                          float* oL, int tid, float scale){
  int eg = (tid & 15) * 4;
  int jg = (tid >> 4) * 4;
  float acc[4][4];
  #pragma unroll
  for (int a = 0; a < 4; ++a){ acc[a][0]=0.f; acc[a][1]=0.f; acc[a][2]=0.f; acc[a][3]=0.f; }
  #pragma unroll 4
  for (int i = 0; i < KDIM; ++i){
    float4 a4 = *(const float4*)&aL[i*68 + eg];
    float4 b4 = *(const float4*)&Wg[i*64 + jg];
    float aa[4] = {a4.x,a4.y,a4.z,a4.w};
    float bb[4] = {b4.x,b4.y,b4.z,b4.w};
    #pragma unroll
    for (int a = 0; a < 4; ++a)
      #pragma unroll
      for (int e = 0; e < 4; ++e)
        acc[a][e] += bb[a]*aa[e];
  }
  #pragma unroll
  for (int a = 0; a < 4; ++a){
    float4 st;
    float x0 = acc[a][0]*scale; st.x = x0/(1.f + expf(-x0));
    float x1 = acc[a][1]*scale; st.y = x1/(1.f + expf(-x1));
    float x2 = acc[a][2]*scale; st.z = x2/(1.f + expf(-x2));
    float x3 = acc[a][3]*scale; st.w = x3/(1.f + expf(-x3));
    *(float4*)&oL[(jg+a)*68 + eg] = st;
  }
}

__launch_bounds__(256)
__global__ void r2_kernel(const float* __restrict__ ef,
                          const float* __restrict__ RW0, const float* __restrict__ RW1,
                          const float* __restrict__ RW2, float* __restrict__ wsf){
  __shared__ float bufA[64*68];
  __shared__ float bufB[64*68];
  __shared__ float r2T[64*68];
  float* R2 = wsf + R2_OFF;
  int tid = threadIdx.x;
  int eb = blockIdx.x * 64;
  float* efT = r2T;  // 8*68 fits; dead after layer 1
  for (int idx = tid; idx < 512; idx += 256){
    int e = idx >> 3, i2 = idx & 7;
    efT[i2*68 + e] = ef[(size_t)(eb+e)*8 + i2];
  }
  __syncthreads();
  mlp_layer<8 >(RW0, efT, bufA, tid, 0.35355339059327373f);
  __syncthreads();
  mlp_layer<64>(RW1, bufA, bufB, tid, 0.125f);
  __syncthreads();
  mlp_layer<64>(RW2, bufB, r2T, tid, 0.125f);
  __syncthreads();
  for (int idx = tid; idx < 4096; idx += 256){
    int e = idx >> 6, i = idx & 63;
    R2[((size_t)(eb+e) << 6) + i] = r2T[i*68 + e];
  }
}

// ---------------------------------------------------------------- CSR build
__global__ void hist_kernel(const int* __restrict__ ei, int* __restrict__ cnt){
  int e = blockIdx.x*256 + threadIdx.x;
  if (e < NEDGES) atomicAdd(&cnt[ei[NEDGES + e]], 1);
}

__global__ void scan_kernel(const int* __restrict__ cnt, int* __restrict__ off){
  __shared__ int part[256];
  __shared__ int partp[256];
  int t = threadIdx.x;
  const int S = 40;  // 256*40 >= 10001
  int s = 0;
  for (int j = 0; j < S; ++j){ int idx = t*S + j; if (idx < NNODES) s += cnt[idx]; }
  part[t] = s;
  __syncthreads();
  if (t == 0){ int run = 0; for (int i = 0; i < 256; ++i){ partp[i] = run; run += part[i]; } }
  __syncthreads();
  int run = partp[t];
  for (int j = 0; j < S; ++j){
    int idx = t*S + j;
    if (idx <= NNODES){
      off[idx] = run;
      if (idx < NNODES) run += cnt[idx];
    }
  }
}

__global__ void fill_kernel(const int* __restrict__ ei, const int* __restrict__ off,
                            int* __restrict__ cur, int* __restrict__ elist){
  int e = blockIdx.x*256 + threadIdx.x;
  if (e < NEDGES){
    int r = ei[NEDGES + e];
    int p = off[r] + atomicAdd(&cur[r], 1);
    elist[p] = e;
  }
}

// ---------------------------------------------------------------- gather helpers
__device__ __forceinline__ float cc_compute(int r, const float* w3L, const float* she){
  float v = 0.f;
  #pragma unroll
  for (int in = 0; in < 10; ++in){
    if (r >= cCCO[in] && r < cCCO[in+1]){
      int rr = r - cCCO[in];
      const int N3v = cN3[in];
      const int N2v = 2*cL2[in] + 1;
      int i = rr / N3v;
      int q = rr - i*N3v;
      float s = 0.f;
      for (int j = 0; j < N2v; ++j)
        s += w3L[in*128 + (i*N2v + j)*N3v + q] * she[cSHO[in] + j];
      v = s;
    }
  }
  return v;
}

template<int IN>
__device__ __forceinline__ void tp_one(const float* __restrict__ cce, const float* __restrict__ he,
                                       int u, float wv, float* accm){
  constexpr int N3v = cN3[IN];
  #pragma unroll
  for (int q = 0; q < N3v; ++q){
    float val;
    if constexpr (cL1[IN] == 0)
      val = cce[q] * he[u];
    else
      val = cce[q]*he[128+u] + cce[N3v+q]*he[256+u] + cce[2*N3v+q]*he[384+u];
    accm[q] += wv * val;
  }
}

// per instruction-pair M: w-GEMM (16-edge register tile) + TP accumulate
template<int M>
__device__ __forceinline__ void do_m(const float* __restrict__ RW3, const float* r2L,
                                     const float* ccL, const float* hL,
                                     int tid, int u, int i0, int eN, float* accm){
  float wv[CHUNK];
  #pragma unroll
  for (int e = 0; e < CHUNK; ++e) wv[e] = 0.f;
  const float* rw = RW3 + 256*M + tid;
  #pragma unroll 4
  for (int i = 0; i < 64; ++i){
    float b = rw[(size_t)i*1280];
    const float* rr = &r2L[i*20];
    float4 r0 = *(const float4*)&rr[0];
    float4 r1 = *(const float4*)&rr[4];
    float4 r2v= *(const float4*)&rr[8];
    float4 r3 = *(const float4*)&rr[12];
    wv[0]  += b*r0.x;  wv[1]  += b*r0.y;  wv[2]  += b*r0.z;  wv[3]  += b*r0.w;
    wv[4]  += b*r1.x;  wv[5]  += b*r1.y;  wv[6]  += b*r1.z;  wv[7]  += b*r1.w;
    wv[8]  += b*r2v.x; wv[9]  += b*r2v.y; wv[10] += b*r2v.z; wv[11] += b*r2v.w;
    wv[12] += b*r3.x;  wv[13] += b*r3.y;  wv[14] += b*r3.z;  wv[15] += b*r3.w;
  }
  #pragma unroll
  for (int e = 0; e < CHUNK; ++e) wv[e] *= 0.125f;  // R_W3 / sqrt(64)
  #pragma unroll
  for (int e = 0; e < CHUNK; ++e){
    if (e < eN){
      if (i0 == 0) tp_one<2*M  >(ccL + e*88 + cCCO[2*M  ], hL + (e<<9), u, wv[e], accm);
      else         tp_one<2*M+1>(ccL + e*88 + cCCO[2*M+1], hL + (e<<9), u, wv[e], accm);
    }
  }
}

template<int IN>
__device__ __forceinline__ void st_cat(float* catL, int u, const float* accm){
  constexpr int N3v = cN3[IN];
  float* p = catL + cCATO[IN] + u*N3v;
  #pragma unroll
  for (int q = 0; q < N3v; ++q) p[q] = accm[q];
}

template<int L>
__device__ __forceinline__ void out_g(const float* catL, const float* __restrict__ Wo,
                                      float* redL, float* __restrict__ outp,
                                      int n, int v, int half){
  constexpr int NI = 2*L + 1;
  constexpr int UL = (L==0 || L==3) ? 256 : 384;
  constexpr int GOv = (L==0) ? 0 : (L==1) ? 256 : (L==2) ? 1408 : 3328;
  constexpr int OOv = (L==0) ? 0 : (L==1) ? 1 : (L==2) ? 4 : 9;
  const float scale = (L==0 || L==3) ? 0.00390625f : 0.0031894435433133252f; // 1/(sqrt(UL)*16)
  float o[NI];
  #pragma unroll
  for (int i = 0; i < NI; ++i) o[i] = 0.f;
  int ul0 = half * (UL/2);
  for (int ul = ul0; ul < ul0 + UL/2; ++ul){
    float wv = Wo[(size_t)ul*128 + v];
    const float* a = catL + GOv + ul*NI;
    #pragma unroll
    for (int i = 0; i < NI; ++i) o[i] += a[i]*wv;
  }
  if (half == 1){
    #pragma unroll
    for (int i = 0; i < NI; ++i) redL[v*NI + i] = o[i];
  }
  __syncthreads();
  if (half == 0){
    float* op = outp + (size_t)n*2048 + v*16 + OOv;
    #pragma unroll
    for (int i = 0; i < NI; ++i) op[i] = (o[i] + redL[v*NI + i]) * scale;
  }
  __syncthreads();
}

// ---------------------------------------------------------------- gather kernel
// one block per receiver node; 16-edge chunks; cat in registers; fused output linear
__launch_bounds__(256, 3)
__global__ void gather_kernel(const float* __restrict__ ea, const int* __restrict__ ei,
                              const float* __restrict__ RW3,
                              const float* __restrict__ Wo0, const float* __restrict__ Wo1,
                              const float* __restrict__ Wo2, const float* __restrict__ Wo3,
                              const float* __restrict__ wsf,
                              const int* __restrict__ off, const int* __restrict__ elist,
                              float* __restrict__ outp){
  __shared__ float poolL[CHUNK*512];   // main loop: hL[16][512]; epilogue: catL[5120]+redL[896]
  __shared__ float w3L[1280];
  __shared__ float r2L[64*20];         // [i][e], pad 20 for conflict-free writes + b128 reads
  __shared__ float shL[CHUNK*16];
  __shared__ float ccL[CHUNK*88];
  __shared__ int   idsL[512];
  __shared__ int   idsC[CHUNK];
  __shared__ int   sC[CHUNK];
  const float* h  = wsf + H_OFF;
  const float* R2 = wsf + R2_OFF;
  int nblk = blockIdx.x, tid = threadIdx.x;
  for (int idx = tid; idx < 1280; idx += 256) w3L[idx] = wsf[W3J_OFF + idx];
  int beg = off[nblk], end = off[nblk+1];
  int deg = end - beg;
  int degc = deg < 512 ? deg : 512;
  for (int idx = tid; idx < degc; idx += 256) idsL[idx] = elist[beg + idx];
  __syncthreads();
  // sort edge ids (deterministic accumulation order); odd-even transposition
  for (int p = 0; p < degc; ++p){
    int i1 = 2*tid + (p & 1);
    if (i1 + 1 < degc){
      int a = idsL[i1], b = idsL[i1+1];
      if (b < a){ idsL[i1] = b; idsL[i1+1] = a; }
    }
    __syncthreads();
  }
  int u = tid & 127;
  int i0 = tid >> 7;           // 0 -> even instrs, 1 -> odd instrs (wave-uniform)
  float acc[5][7];
  #pragma unroll
  for (int m = 0; m < 5; ++m)
    #pragma unroll
    for (int q = 0; q < 7; ++q) acc[m][q] = 0.f;

  for (int base = 0; base < deg; base += CHUNK){
    int eN = deg - base; if (eN > CHUNK) eN = CHUNK;
    __syncthreads();  // protect LDS reuse vs previous chunk's reads
    if (tid < CHUNK){
      int id = 0;
      int k = base + tid;
      if (tid < eN) id = (k < degc) ? idsL[k] : elist[beg + k];
      idsC[tid] = id;
      sC[tid]   = ei[id];       // sender
    }
    __syncthreads();
    // h rows -> LDS (float4 coalesced)
    for (int idx = tid; idx < (eN << 7); idx += 256){
      int e = idx >> 7, j4 = idx & 127;
      *(float4*)&poolL[(e << 9) + j4*4] = *(const float4*)&h[((size_t)sC[e] << 9) + j4*4];
    }
    // r2 -> LDS transposed [i][e] (global coalesced over i; pad-20 writes conflict-free)
    for (int idx = tid; idx < (eN << 6); idx += 256){
      int e = idx >> 6, i = idx & 63;
      r2L[i*20 + e] = R2[((size_t)idsC[e] << 6) + i];
    }
    // sh
    for (int idx = tid; idx < (eN << 4); idx += 256){
      int e = idx >> 4, j = idx & 15;
      shL[e*16 + j] = ea[((size_t)idsC[e] << 4) + j];
    }
    __syncthreads();
    // cc from sh
    for (int idx = tid; idx < eN*88; idx += 256){
      int e = idx / 88, r = idx - e*88;
      ccL[e*88 + r] = cc_compute(r, w3L, shL + e*16);
    }
    __syncthreads();
    // 5 instruction-pairs: w-GEMM (register tile) + TP accumulate
    do_m<0>(RW3, r2L, ccL, poolL, tid, u, i0, eN, acc[0]);
    do_m<1>(RW3, r2L, ccL, poolL, tid, u, i0, eN, acc[1]);
    do_m<2>(RW3, r2L, ccL, poolL, tid, u, i0, eN, acc[2]);
    do_m<3>(RW3, r2L, ccL, poolL, tid, u, i0, eN, acc[3]);
    do_m<4>(RW3, r2L, ccL, poolL, tid, u, i0, eN, acc[4]);
  }
  __syncthreads();
  // epilogue: cat row -> LDS (aliases hL region), then fused output linear
  float* catL = poolL;
  float* redL = poolL + 5120;
  if (i0 == 0){
    st_cat<0>(catL, u, acc[0]);
    st_cat<2>(catL, u, acc[1]);
    st_cat<4>(catL, u, acc[2]);
    st_cat<6>(catL, u, acc[3]);
    st_cat<8>(catL, u, acc[4]);
  } else {
    st_cat<1>(catL, u, acc[0]);
    st_cat<3>(catL, u, acc[1]);
    st_cat<5>(catL, u, acc[2]);
    st_cat<7>(catL, u, acc[3]);
    st_cat<9>(catL, u, acc[4]);
  }
  __syncthreads();
  out_g<0>(catL, Wo0, redL, outp, nblk, u, i0);
  out_g<1>(catL, Wo1, redL, outp, nblk, u, i0);
  out_g<2>(catL, Wo2, redL, outp, nblk, u, i0);
  out_g<3>(catL, Wo3, redL, outp, nblk, u, i0);
}

// ---------------------------------------------------------------- launch
extern "C" void kernel_launch(void* const* d_in, const int* in_sizes, int n_in,
                              void* d_out, int out_size, void* d_ws, size_t ws_size,
                              hipStream_t stream){
  const float* nf  = (const float*)d_in[0];
  const float* ea  = (const float*)d_in[2];
  const float* ef  = (const float*)d_in[3];
  const int*   ei  = (const int*)d_in[4];
  const float* W0  = (const float*)d_in[5];
  const float* W1  = (const float*)d_in[6];
  const float* RW0 = (const float*)d_in[7];
  const float* RW1 = (const float*)d_in[8];
  const float* RW2 = (const float*)d_in[9];
  const float* RW3 = (const float*)d_in[10];
  const float* Wo0 = (const float*)d_in[11];
  const float* Wo1 = (const float*)d_in[12];
  const float* Wo2 = (const float*)d_in[13];
  const float* Wo3 = (const float*)d_in[14];
  float* wsf  = (float*)d_ws;
  int*   wsi  = (int*)d_ws;
  float* outp = (float*)d_out;

  hipMemsetAsync(wsi + CNT_W, 0, 2*NNODES*sizeof(int), stream);  // cnt + cur
  w3j_kernel<<<10, 128, 0, stream>>>(wsf);
  node_kernel<<<157, 256, 0, stream>>>(nf, W0, W1, wsf);
  r2_kernel<<<2048, 256, 0, stream>>>(ef, RW0, RW1, RW2, wsf);
  hist_kernel<<<512, 256, 0, stream>>>(ei, wsi + CNT_W);
  scan_kernel<<<1, 256, 0, stream>>>(wsi + CNT_W, wsi + OFF_W);
  fill_kernel<<<512, 256, 0, stream>>>(ei, wsi + OFF_W, wsi + CUR_W, wsi + ELIST_W);
  gather_kernel<<<NNODES, 256, 0, stream>>>(ea, ei, RW3, Wo0, Wo1, Wo2, Wo3,
                                            wsf, wsi + OFF_W, wsi + ELIST_W, outp);
}

// Round 4
// 1892.985 us; speedup vs baseline: 20.9924x; 1.1404x over previous
//
#include <hip/hip_runtime.h>
#include <math.h>

#define NNODES 10000
#define NEDGES 131072
#define CHUNK 16

// ws layout (word offsets, 4B words)
#define W3J_OFF 0                          // 1280 floats
#define H_OFF   1280                       // NNODES*512 floats
#define R2_OFF  (1280 + NNODES*512)        // NEDGES*64 floats
#define CSR_W   (R2_OFF + NEDGES*64)
#define CNT_W   CSR_W                      // 10000 ints
#define CUR_W   (CSR_W + NNODES)           // 10000 ints
#define OFF_W   (CSR_W + 2*NNODES)         // 10001 ints
#define ELIST_W (CSR_W + 2*NNODES + NNODES + 1)  // NEDGES ints

// instruction tables (compile-time)
constexpr int cL1[10]  = {0,1,0,1,1,0,1,1,0,1};
constexpr int cL2[10]  = {0,1,1,0,2,2,1,3,3,2};
constexpr int cN3[10]  = {1,1,3,3,3,5,5,5,7,7};
constexpr int cSHO[10] = {0,1,1,0,4,4,1,9,9,4};
constexpr int cCCO[11] = {0,1,4,7,16,25,30,45,60,67,88};
constexpr int cCATO[10]= {0,128,256,640,1024,1408,2048,2688,3328,4224};

// ---------------------------------------------------------------- w3j kernel
struct cpx { double re, im; };
__device__ inline cpx cmul(cpx a, cpx b){ return {a.re*b.re - a.im*b.im, a.re*b.im + a.im*b.re}; }

__device__ double dfact(int n){ double r = 1.0; for (int i = 2; i <= n; ++i) r *= (double)i; return r; }

__device__ double cgval(int j1,int j2,int j3,int m1,int m2){
  int m3 = m1 + m2;
  if (m3 > j3 || m3 < -j3) return 0.0;
  double pref = (double)(2*j3+1) * dfact(j3+j1-j2)*dfact(j3-j1+j2)*dfact(j1+j2-j3)/dfact(j1+j2+j3+1);
  pref *= dfact(j3+m3)*dfact(j3-m3)*dfact(j1-m1)*dfact(j1+m1)*dfact(j2-m2)*dfact(j2+m2);
  int k0 = 0; if (-(j3-j2+m1) > k0) k0 = -(j3-j2+m1); if (-(j3-j1-m2) > k0) k0 = -(j3-j1-m2);
  int k1 = j1+j2-j3; if (j1-m1 < k1) k1 = j1-m1; if (j2+m2 < k1) k1 = j2+m2;
  double s = 0.0;
  for (int k = k0; k <= k1; ++k){
    double d = dfact(k)*dfact(j1+j2-j3-k)*dfact(j1-m1-k)*dfact(j2+m2-k)*dfact(j3-j2+m1+k)*dfact(j3-j1-m2+k);
    s += ((k & 1) ? -1.0 : 1.0) / d;
  }
  return sqrt(pref) * s;
}

__device__ cpx qval(int l, int a, int col){
  int m = a - l;
  const double is2 = 0.70710678118654752440;
  double re = 0.0, im = 0.0;
  if (m < 0){
    if (col == l - m) re = is2;
    else if (col == l + m) im = -is2;
  } else if (m == 0){
    if (col == l) re = 1.0;
  } else {
    double sgn = (m & 1) ? -1.0 : 1.0;
    if (col == l + m) re = sgn * is2;
    else if (col == l - m) im = sgn * is2;
  }
  double pr, pi;  // (-i)^l
  switch (l & 3){ case 0: pr=1; pi=0; break; case 1: pr=0; pi=-1; break; case 2: pr=-1; pi=0; break; default: pr=0; pi=1; }
  return { re*pr - im*pi, re*pi + im*pr };
}

__global__ void w3j_kernel(float* ws){
  __shared__ double red[128];
  __shared__ int useConjS;
  __shared__ double normS;
  const int IL[10][3] = {{0,0,0},{1,1,0},{0,1,1},{1,0,1},{1,2,1},{0,2,2},{1,1,2},{1,3,2},{0,3,3},{1,2,3}};
  int k = blockIdx.x;
  int l1 = IL[k][0], l2 = IL[k][1], l3 = IL[k][2];
  int n1 = 2*l1+1, n2 = 2*l2+1, n3 = 2*l3+1;
  int nent = n1*n2*n3;
  int tid = threadIdx.x;
  double dcr=0, dci=0, dpr=0, dpi=0;
  if (tid < nent){
    int i = tid/(n2*n3), j = (tid/n3)%n2, kk = tid%n3;
    for (int a = 0; a < n1; ++a){
      for (int b = 0; b < n2; ++b){
        int m1 = a - l1, m2 = b - l2, m3 = m1 + m2;
        if (m3 < -l3 || m3 > l3) continue;
        int c = m3 + l3;
        double C = cgval(l1,l2,l3,m1,m2);
        if (C == 0.0) continue;
        cpx q1 = qval(l1,a,i), q2 = qval(l2,b,j), q3 = qval(l3,c,kk);
        cpx t = cmul(q1,q2);
        cpx q3c = { q3.re, -q3.im };
        cpx tc = cmul(t, q3c);
        cpx tp = cmul(t, q3);
        dcr += C*tc.re; dci += C*tc.im;
        dpr += C*tp.re; dpi += C*tp.im;
      }
    }
  }
  red[tid] = (tid < nent) ? fabs(dci) : 0.0;
  __syncthreads();
  if (tid == 0){
    double mx = 0.0;
    for (int t = 0; t < 128; ++t) if (red[t] > mx) mx = red[t];
    useConjS = (mx < 1e-9) ? 1 : 0;
  }
  __syncthreads();
  double re = useConjS ? dcr : dpr;
  red[tid] = (tid < nent) ? re*re : 0.0;
  __syncthreads();
  if (tid == 0){
    double s = 0.0;
    for (int t = 0; t < 128; ++t) s += red[t];
    normS = sqrt(s);
  }
  __syncthreads();
  if (tid < nent)
    ws[W3J_OFF + k*128 + tid] = (float)(re / normS * sqrt((double)(2*l3+1)));  // fold sqrt(2l3+1)
}

// ---------------------------------------------------------------- node transform
// h[n][512]: [0..128) = h0[v]; [128 + i*128 + v] = h1[n][v][i]
__launch_bounds__(256, 4)
__global__ void node_kernel(const float* __restrict__ nf, const float* __restrict__ W0,
                            const float* __restrict__ W1, float* __restrict__ ws){
  __shared__ float AtL[128*68];
  float* h = ws + H_OFF;
  int tid = threadIdx.x;
  int n0 = blockIdx.x * 64;
  const float rs = 0.08838834764831845f; // 1/sqrt(128)
  int mg = (tid & 15) * 4;
  int vg = (tid >> 4) * 8;
  for (int c = 0; c < 4; ++c){
    __syncthreads();
    for (int idx = tid; idx < 8192; idx += 256){
      int m = idx >> 7, u = idx & 127;
      int node = n0 + m;
      float v = 0.f;
      if (node < NNODES)
        v = (c == 0) ? nf[(size_t)node*512 + u] : nf[(size_t)node*512 + 128 + u*3 + (c-1)];
      AtL[u*68 + m] = v;
    }
    __syncthreads();
    const float* W = (c == 0) ? W0 : W1;
    float acc[8][4];
    #pragma unroll
    for (int a = 0; a < 8; ++a){ acc[a][0]=0.f; acc[a][1]=0.f; acc[a][2]=0.f; acc[a][3]=0.f; }
    for (int u = 0; u < 128; ++u){
      float4 am = *(const float4*)&AtL[u*68 + mg];
      const float* wr = W + u*128 + vg;
      float4 b0 = *(const float4*)wr;
      float4 b1 = *(const float4*)(wr + 4);
      float aa[4] = {am.x, am.y, am.z, am.w};
      float bb[8] = {b0.x,b0.y,b0.z,b0.w,b1.x,b1.y,b1.z,b1.w};
      #pragma unroll
      for (int a = 0; a < 8; ++a)
        #pragma unroll
        for (int e = 0; e < 4; ++e)
          acc[a][e] += bb[a]*aa[e];
    }
    #pragma unroll
    for (int e = 0; e < 4; ++e){
      int node = n0 + mg + e;
      if (node < NNODES){
        float4 s0 = {acc[0][e]*rs, acc[1][e]*rs, acc[2][e]*rs, acc[3][e]*rs};
        float4 s1 = {acc[4][e]*rs, acc[5][e]*rs, acc[6][e]*rs, acc[7][e]*rs};
        *(float4*)&h[(size_t)node*512 + c*128 + vg] = s0;
        *(float4*)&h[(size_t)node*512 + c*128 + vg + 4] = s1;
      }
    }
  }
}

// ---------------------------------------------------------------- radial MLP (r2)
template<int KDIM>
__device__ __forceinline__ void mlp_layer(const float* __restrict__ Wg, const float* aL,
                                          float* oL, int tid, float scale){
  int eg = (tid & 15) * 4;
  int jg = (tid >> 4) * 4;
  float acc[4][4];
  #pragma unroll
  for (int a = 0; a < 4; ++a){ acc[a][0]=0.f; acc[a][1]=0.f; acc[a][2]=0.f; acc[a][3]=0.f; }
  #pragma unroll 4
  for (int i = 0; i < KDIM; ++i){
    float4 a4 = *(const float4*)&aL[i*68 + eg];
    float4 b4 = *(const float4*)&Wg[i*64 + jg];
    float aa[4] = {a4.x,a4.y,a4.z,a4.w};
    float bb[4] = {b4.x,b4.y,b4.z,b4.w};
    #pragma unroll
    for (int a = 0; a < 4; ++a)
      #pragma unroll
      for (int e = 0; e < 4; ++e)
        acc[a][e] += bb[a]*aa[e];
  }
  #pragma unroll
  for (int a = 0; a < 4; ++a){
    float4 st;
    float x0 = acc[a][0]*scale; st.x = x0/(1.f + expf(-x0));
    float x1 = acc[a][1]*scale; st.y = x1/(1.f + expf(-x1));
    float x2 = acc[a][2]*scale; st.z = x2/(1.f + expf(-x2));
    float x3 = acc[a][3]*scale; st.w = x3/(1.f + expf(-x3));
    *(float4*)&oL[(jg+a)*68 + eg] = st;
  }
}

__launch_bounds__(256)
__global__ void r2_kernel(const float* __restrict__ ef,
                          const float* __restrict__ RW0, const float* __restrict__ RW1,
                          const float* __restrict__ RW2, float* __restrict__ wsf){
  __shared__ float bufA[64*68];
  __shared__ float bufB[64*68];
  __shared__ float r2T[64*68];
  float* R2 = wsf + R2_OFF;
  int tid = threadIdx.x;
  int eb = blockIdx.x * 64;
  float* efT = r2T;  // 8*68 fits; dead after layer 1
  for (int idx = tid; idx < 512; idx += 256){
    int e = idx >> 3, i2 = idx & 7;
    efT[i2*68 + e] = ef[(size_t)(eb+e)*8 + i2];
  }
  __syncthreads();
  mlp_layer<8 >(RW0, efT, bufA, tid, 0.35355339059327373f);
  __syncthreads();
  mlp_layer<64>(RW1, bufA, bufB, tid, 0.125f);
  __syncthreads();
  mlp_layer<64>(RW2, bufB, r2T, tid, 0.125f);
  __syncthreads();
  for (int idx = tid; idx < 4096; idx += 256){
    int e = idx >> 6, i = idx & 63;
    R2[((size_t)(eb+e) << 6) + i] = r2T[i*68 + e];
  }
}

// ---------------------------------------------------------------- CSR build
__global__ void hist_kernel(const int* __restrict__ ei, int* __restrict__ cnt){
  int e = blockIdx.x*256 + threadIdx.x;
  if (e < NEDGES) atomicAdd(&cnt[ei[NEDGES + e]], 1);
}

__global__ void scan_kernel(const int* __restrict__ cnt, int* __restrict__ off){
  __shared__ int part[256];
  __shared__ int partp[256];
  int t = threadIdx.x;
  const int S = 40;  // 256*40 >= 10001
  int s = 0;
  for (int j = 0; j < S; ++j){ int idx = t*S + j; if (idx < NNODES) s += cnt[idx]; }
  part[t] = s;
  __syncthreads();
  if (t == 0){ int run = 0; for (int i = 0; i < 256; ++i){ partp[i] = run; run += part[i]; } }
  __syncthreads();
  int run = partp[t];
  for (int j = 0; j < S; ++j){
    int idx = t*S + j;
    if (idx <= NNODES){
      off[idx] = run;
      if (idx < NNODES) run += cnt[idx];
    }
  }
}

__global__ void fill_kernel(const int* __restrict__ ei, const int* __restrict__ off,
                            int* __restrict__ cur, int* __restrict__ elist){
  int e = blockIdx.x*256 + threadIdx.x;
  if (e < NEDGES){
    int r = ei[NEDGES + e];
    int p = off[r] + atomicAdd(&cur[r], 1);
    elist[p] = e;
  }
}

// ---------------------------------------------------------------- gather helpers
__device__ __forceinline__ float cc_compute(int r, const float* w3L, const float* she){
  float v = 0.f;
  #pragma unroll
  for (int in = 0; in < 10; ++in){
    if (r >= cCCO[in] && r < cCCO[in+1]){
      int rr = r - cCCO[in];
      const int N3v = cN3[in];
      const int N2v = 2*cL2[in] + 1;
      int i = rr / N3v;
      int q = rr - i*N3v;
      float s = 0.f;
      for (int j = 0; j < N2v; ++j)
        s += w3L[in*128 + (i*N2v + j)*N3v + q] * she[cSHO[in] + j];
      v = s;
    }
  }
  return v;
}

// TP for one edge, one instruction; h read directly from global (L1/L2-hot)
template<int IN>
__device__ __forceinline__ void tp_g(const float* __restrict__ cce, const float* __restrict__ hp,
                                     float wv, float* accm){
  constexpr int N3v = cN3[IN];
  if constexpr (cL1[IN] == 0){
    float wh = wv * hp[0];
    #pragma unroll
    for (int q = 0; q < N3v; ++q) accm[q] += cce[q] * wh;
  } else {
    float wa = wv * hp[128];
    float wb = wv * hp[256];
    float wc = wv * hp[384];
    #pragma unroll
    for (int q = 0; q < N3v; ++q)
      accm[q] += cce[q]*wa + cce[N3v+q]*wb + cce[2*N3v+q]*wc;
  }
}

// per instruction-pair M: w-GEMM (16-edge register tile) + TP accumulate
template<int M>
__device__ __forceinline__ void do_m(const float* __restrict__ RW3, const float* r2L,
                                     const float* ccL, const float* __restrict__ h,
                                     const int* sC, int tid, int u, int i0, float* accm){
  float wv[CHUNK];
  #pragma unroll
  for (int e = 0; e < CHUNK; ++e) wv[e] = 0.f;
  const float* rw = RW3 + 256*M + tid;
  #pragma unroll 4
  for (int i = 0; i < 64; ++i){
    float b = rw[(size_t)i*1280];
    const float* rr = &r2L[i*20];
    float4 r0 = *(const float4*)&rr[0];
    float4 r1 = *(const float4*)&rr[4];
    float4 r2v= *(const float4*)&rr[8];
    float4 r3 = *(const float4*)&rr[12];
    wv[0]  += b*r0.x;  wv[1]  += b*r0.y;  wv[2]  += b*r0.z;  wv[3]  += b*r0.w;
    wv[4]  += b*r1.x;  wv[5]  += b*r1.y;  wv[6]  += b*r1.z;  wv[7]  += b*r1.w;
    wv[8]  += b*r2v.x; wv[9]  += b*r2v.y; wv[10] += b*r2v.z; wv[11] += b*r2v.w;
    wv[12] += b*r3.x;  wv[13] += b*r3.y;  wv[14] += b*r3.z;  wv[15] += b*r3.w;
  }
  #pragma unroll
  for (int e = 0; e < CHUNK; ++e) wv[e] *= 0.125f;  // R_W3 / sqrt(64)
  // TP in two 8-edge halves (limits register spike from hoisted h loads)
  #pragma unroll
  for (int eh = 0; eh < 2; ++eh){
    if (i0 == 0){
      #pragma unroll
      for (int e8 = 0; e8 < 8; ++e8){
        int e = eh*8 + e8;
        const float* hp = h + ((size_t)sC[e] << 9) + u;
        tp_g<2*M>(ccL + e*88 + cCCO[2*M], hp, wv[e], accm);
      }
    } else {
      #pragma unroll
      for (int e8 = 0; e8 < 8; ++e8){
        int e = eh*8 + e8;
        const float* hp = h + ((size_t)sC[e] << 9) + u;
        tp_g<2*M+1>(ccL + e*88 + cCCO[2*M+1], hp, wv[e], accm);
      }
    }
  }
}

template<int IN>
__device__ __forceinline__ void st_cat(float* catL, int u, const float* accm){
  constexpr int N3v = cN3[IN];
  float* p = catL + cCATO[IN] + u*N3v;
  #pragma unroll
  for (int q = 0; q < N3v; ++q) p[q] = accm[q];
}

template<int L>
__device__ __forceinline__ void out_g(const float* catL, const float* __restrict__ Wo,
                                      float* redL, float* __restrict__ outp,
                                      int n, int v, int half){
  constexpr int NI = 2*L + 1;
  constexpr int UL = (L==0 || L==3) ? 256 : 384;
  constexpr int GOv = (L==0) ? 0 : (L==1) ? 256 : (L==2) ? 1408 : 3328;
  constexpr int OOv = (L==0) ? 0 : (L==1) ? 1 : (L==2) ? 4 : 9;
  const float scale = (L==0 || L==3) ? 0.00390625f : 0.0031894435433133252f; // 1/(sqrt(UL)*16)
  float o[NI];
  #pragma unroll
  for (int i = 0; i < NI; ++i) o[i] = 0.f;
  int ul0 = half * (UL/2);
  for (int ul = ul0; ul < ul0 + UL/2; ++ul){
    float wv = Wo[(size_t)ul*128 + v];
    const float* a = catL + GOv + ul*NI;
    #pragma unroll
    for (int i = 0; i < NI; ++i) o[i] += a[i]*wv;
  }
  if (half == 1){
    #pragma unroll
    for (int i = 0; i < NI; ++i) redL[v*NI + i] = o[i];
  }
  __syncthreads();
  if (half == 0){
    float* op = outp + (size_t)n*2048 + v*16 + OOv;
    #pragma unroll
    for (int i = 0; i < NI; ++i) op[i] = (o[i] + redL[v*NI + i]) * scale;
  }
  __syncthreads();
}

// ---------------------------------------------------------------- gather kernel
// one block per receiver node; 16-edge chunks; LDS union (main loop / epilogue)
__launch_bounds__(256, 4)
__global__ void gather_kernel(const float* __restrict__ ea, const int* __restrict__ ei,
                              const float* __restrict__ RW3,
                              const float* __restrict__ Wo0, const float* __restrict__ Wo1,
                              const float* __restrict__ Wo2, const float* __restrict__ Wo3,
                              const float* __restrict__ wsf,
                              const int* __restrict__ off, const int* __restrict__ elist,
                              float* __restrict__ outp){
  __shared__ float smemF[6016];          // 24 KB union
  // main-loop region
  int*   idsL = (int*)smemF;             // 512
  int*   idsC = (int*)(smemF + 512);     // 16
  int*   sC   = (int*)(smemF + 528);     // 16
  float* w3L  = smemF + 544;             // 1280
  float* r2L  = smemF + 1824;            // 64*20 = 1280 ([i][e], pad 20)
  float* shL  = smemF + 3104;            // 16*16 = 256
  float* ccL  = smemF + 3360;            // 16*88 = 1408  (ends 4768)
  // epilogue region (aliases everything above)
  float* catL = smemF;                   // 5120
  float* redL = smemF + 5120;            // 896

  const float* h  = wsf + H_OFF;
  const float* R2 = wsf + R2_OFF;
  int nblk = blockIdx.x, tid = threadIdx.x;
  for (int idx = tid; idx < 1280; idx += 256) w3L[idx] = wsf[W3J_OFF + idx];
  int beg = off[nblk], end = off[nblk+1];
  int deg = end - beg;
  int degc = deg < 512 ? deg : 512;
  for (int idx = tid; idx < degc; idx += 256) idsL[idx] = elist[beg + idx];
  __syncthreads();
  // rank-sort (edge ids distinct): 2 passes over <=2 elements per thread
  {
    int v0 = 0, r0 = 0, v1 = 0, r1 = 0;
    bool a0 = tid < degc, a1 = tid + 256 < degc;
    if (a0){ v0 = idsL[tid]; int r = 0; for (int j = 0; j < degc; ++j) r += (idsL[j] < v0); r0 = r; }
    if (a1){ v1 = idsL[tid+256]; int r = 0; for (int j = 0; j < degc; ++j) r += (idsL[j] < v1); r1 = r; }
    __syncthreads();
    if (a0) idsL[r0] = v0;
    if (a1) idsL[r1] = v1;
  }

  int u = tid & 127;
  int i0 = tid >> 7;           // 0 -> even instrs, 1 -> odd instrs (wave-uniform)
  float acc0[1] = {0.f};
  float acc1[3] = {0.f,0.f,0.f};
  float acc2[5] = {0.f,0.f,0.f,0.f,0.f};
  float acc3[5] = {0.f,0.f,0.f,0.f,0.f};
  float acc4[7] = {0.f,0.f,0.f,0.f,0.f,0.f,0.f};

  for (int base = 0; base < deg; base += CHUNK){
    int eN = deg - base; if (eN > CHUNK) eN = CHUNK;
    __syncthreads();  // protect LDS reuse vs previous chunk's reads
    if (tid < CHUNK){
      int k = base + tid;
      int id;
      if (tid < eN) id = (k < degc) ? idsL[k] : elist[beg + k];
      else          id = (base < degc) ? idsL[base] : elist[beg + base];  // pad: any valid edge
      idsC[tid] = id;
      sC[tid]   = ei[id];       // sender
    }
    __syncthreads();
    // r2 -> LDS transposed [i][e]; ZERO for pad edges (=> wv==0 kills their TP contribution)
    for (int idx = tid; idx < (CHUNK << 6); idx += 256){
      int e = idx >> 6, i = idx & 63;
      r2L[i*20 + e] = (e < eN) ? R2[((size_t)idsC[e] << 6) + i] : 0.f;
    }
    // sh (pad edges get valid-but-unused data)
    for (int idx = tid; idx < (CHUNK << 4); idx += 256){
      int e = idx >> 4, j = idx & 15;
      shL[e*16 + j] = ea[((size_t)idsC[e] << 4) + j];
    }
    __syncthreads();
    // cc from sh (all 16 edges; pad contributes *0 later)
    for (int idx = tid; idx < CHUNK*88; idx += 256){
      int e = idx / 88, r = idx - e*88;
      ccL[e*88 + r] = cc_compute(r, w3L, shL + e*16);
    }
    __syncthreads();
    // 5 instruction-pairs: w-GEMM (register tile) + TP accumulate (h direct from global)
    do_m<0>(RW3, r2L, ccL, h, sC, tid, u, i0, acc0);
    do_m<1>(RW3, r2L, ccL, h, sC, tid, u, i0, acc1);
    do_m<2>(RW3, r2L, ccL, h, sC, tid, u, i0, acc2);
    do_m<3>(RW3, r2L, ccL, h, sC, tid, u, i0, acc3);
    do_m<4>(RW3, r2L, ccL, h, sC, tid, u, i0, acc4);
  }
  __syncthreads();
  // epilogue: cat row -> LDS union, then fused output linear
  if (i0 == 0){
    st_cat<0>(catL, u, acc0);
    st_cat<2>(catL, u, acc1);
    st_cat<4>(catL, u, acc2);
    st_cat<6>(catL, u, acc3);
    st_cat<8>(catL, u, acc4);
  } else {
    st_cat<1>(catL, u, acc0);
    st_cat<3>(catL, u, acc1);
    st_cat<5>(catL, u, acc2);
    st_cat<7>(catL, u, acc3);
    st_cat<9>(catL, u, acc4);
  }
  __syncthreads();
  out_g<0>(catL, Wo0, redL, outp, nblk, u, i0);
  out_g<1>(catL, Wo1, redL, outp, nblk, u, i0);
  out_g<2>(catL, Wo2, redL, outp, nblk, u, i0);
  out_g<3>(catL, Wo3, redL, outp, nblk, u, i0);
}

// ---------------------------------------------------------------- launch
extern "C" void kernel_launch(void* const* d_in, const int* in_sizes, int n_in,
                              void* d_out, int out_size, void* d_ws, size_t ws_size,
                              hipStream_t stream){
  const float* nf  = (const float*)d_in[0];
  const float* ea  = (const float*)d_in[2];
  const float* ef  = (const float*)d_in[3];
  const int*   ei  = (const int*)d_in[4];
  const float* W0  = (const float*)d_in[5];
  const float* W1  = (const float*)d_in[6];
  const float* RW0 = (const float*)d_in[7];
  const float* RW1 = (const float*)d_in[8];
  const float* RW2 = (const float*)d_in[9];
  const float* RW3 = (const float*)d_in[10];
  const float* Wo0 = (const float*)d_in[11];
  const float* Wo1 = (const float*)d_in[12];
  const float* Wo2 = (const float*)d_in[13];
  const float* Wo3 = (const float*)d_in[14];
  float* wsf  = (float*)d_ws;
  int*   wsi  = (int*)d_ws;
  float* outp = (float*)d_out;

  hipMemsetAsync(wsi + CNT_W, 0, 2*NNODES*sizeof(int), stream);  // cnt + cur
  w3j_kernel<<<10, 128, 0, stream>>>(wsf);
  node_kernel<<<157, 256, 0, stream>>>(nf, W0, W1, wsf);
  r2_kernel<<<2048, 256, 0, stream>>>(ef, RW0, RW1, RW2, wsf);
  hist_kernel<<<512, 256, 0, stream>>>(ei, wsi + CNT_W);
  scan_kernel<<<1, 256, 0, stream>>>(wsi + CNT_W, wsi + OFF_W);
  fill_kernel<<<512, 256, 0, stream>>>(ei, wsi + OFF_W, wsi + CUR_W, wsi + ELIST_W);
  gather_kernel<<<NNODES, 256, 0, stream>>>(ea, ei, RW3, Wo0, Wo1, Wo2, Wo3,
                                            wsf, wsi + OFF_W, wsi + ELIST_W, outp);
}

// Round 5
// 1791.752 us; speedup vs baseline: 22.1784x; 1.0565x over previous
//
#include <hip/hip_runtime.h>
#include <math.h>

#define NNODES 10000
#define NEDGES 131072
#define CHUNK 16

// ws layout (word offsets, 4B words)
#define W3J_OFF 0                                   // 1280 floats
#define H_OFF   1280                                // NNODES*512
#define R2_OFF  (1280 + NNODES*512)                 // NEDGES*64
#define CC_OFF  (R2_OFF + NEDGES*64)                // NEDGES*88
#define CSR_W   (CC_OFF + NEDGES*88)
#define CNT_W   CSR_W                               // 10000 ints
#define CUR_W   (CSR_W + NNODES)                    // 10000 ints
#define OFF_W   (CSR_W + 2*NNODES)                  // 10001 ints
#define ELIST_W (CSR_W + 2*NNODES + NNODES + 1)     // NEDGES ints

// instruction tables (compile-time)
constexpr int cL1[10]  = {0,1,0,1,1,0,1,1,0,1};
constexpr int cL2[10]  = {0,1,1,0,2,2,1,3,3,2};
constexpr int cN3[10]  = {1,1,3,3,3,5,5,5,7,7};
constexpr int cSHO[10] = {0,1,1,0,4,4,1,9,9,4};
constexpr int cCCO[11] = {0,1,4,7,16,25,30,45,60,67,88};
constexpr int cCATO[10]= {0,128,256,640,1024,1408,2048,2688,3328,4224};

// ---------------------------------------------------------------- w3j kernel
struct cpx { double re, im; };
__device__ inline cpx cmul(cpx a, cpx b){ return {a.re*b.re - a.im*b.im, a.re*b.im + a.im*b.re}; }

__device__ double dfact(int n){ double r = 1.0; for (int i = 2; i <= n; ++i) r *= (double)i; return r; }

__device__ double cgval(int j1,int j2,int j3,int m1,int m2){
  int m3 = m1 + m2;
  if (m3 > j3 || m3 < -j3) return 0.0;
  double pref = (double)(2*j3+1) * dfact(j3+j1-j2)*dfact(j3-j1+j2)*dfact(j1+j2-j3)/dfact(j1+j2+j3+1);
  pref *= dfact(j3+m3)*dfact(j3-m3)*dfact(j1-m1)*dfact(j1+m1)*dfact(j2-m2)*dfact(j2+m2);
  int k0 = 0; if (-(j3-j2+m1) > k0) k0 = -(j3-j2+m1); if (-(j3-j1-m2) > k0) k0 = -(j3-j1-m2);
  int k1 = j1+j2-j3; if (j1-m1 < k1) k1 = j1-m1; if (j2+m2 < k1) k1 = j2+m2;
  double s = 0.0;
  for (int k = k0; k <= k1; ++k){
    double d = dfact(k)*dfact(j1+j2-j3-k)*dfact(j1-m1-k)*dfact(j2+m2-k)*dfact(j3-j2+m1+k)*dfact(j3-j1-m2+k);
    s += ((k & 1) ? -1.0 : 1.0) / d;
  }
  return sqrt(pref) * s;
}

__device__ cpx qval(int l, int a, int col){
  int m = a - l;
  const double is2 = 0.70710678118654752440;
  double re = 0.0, im = 0.0;
  if (m < 0){
    if (col == l - m) re = is2;
    else if (col == l + m) im = -is2;
  } else if (m == 0){
    if (col == l) re = 1.0;
  } else {
    double sgn = (m & 1) ? -1.0 : 1.0;
    if (col == l + m) re = sgn * is2;
    else if (col == l - m) im = sgn * is2;
  }
  double pr, pi;  // (-i)^l
  switch (l & 3){ case 0: pr=1; pi=0; break; case 1: pr=0; pi=-1; break; case 2: pr=-1; pi=0; break; default: pr=0; pi=1; }
  return { re*pr - im*pi, re*pi + im*pr };
}

__global__ void w3j_kernel(float* ws){
  __shared__ double red[128];
  __shared__ int useConjS;
  __shared__ double normS;
  const int IL[10][3] = {{0,0,0},{1,1,0},{0,1,1},{1,0,1},{1,2,1},{0,2,2},{1,1,2},{1,3,2},{0,3,3},{1,2,3}};
  int k = blockIdx.x;
  int l1 = IL[k][0], l2 = IL[k][1], l3 = IL[k][2];
  int n1 = 2*l1+1, n2 = 2*l2+1, n3 = 2*l3+1;
  int nent = n1*n2*n3;
  int tid = threadIdx.x;
  double dcr=0, dci=0, dpr=0, dpi=0;
  if (tid < nent){
    int i = tid/(n2*n3), j = (tid/n3)%n2, kk = tid%n3;
    for (int a = 0; a < n1; ++a){
      for (int b = 0; b < n2; ++b){
        int m1 = a - l1, m2 = b - l2, m3 = m1 + m2;
        if (m3 < -l3 || m3 > l3) continue;
        int c = m3 + l3;
        double C = cgval(l1,l2,l3,m1,m2);
        if (C == 0.0) continue;
        cpx q1 = qval(l1,a,i), q2 = qval(l2,b,j), q3 = qval(l3,c,kk);
        cpx t = cmul(q1,q2);
        cpx q3c = { q3.re, -q3.im };
        cpx tc = cmul(t, q3c);
        cpx tp = cmul(t, q3);
        dcr += C*tc.re; dci += C*tc.im;
        dpr += C*tp.re; dpi += C*tp.im;
      }
    }
  }
  red[tid] = (tid < nent) ? fabs(dci) : 0.0;
  __syncthreads();
  if (tid == 0){
    double mx = 0.0;
    for (int t = 0; t < 128; ++t) if (red[t] > mx) mx = red[t];
    useConjS = (mx < 1e-9) ? 1 : 0;
  }
  __syncthreads();
  double re = useConjS ? dcr : dpr;
  red[tid] = (tid < nent) ? re*re : 0.0;
  __syncthreads();
  if (tid == 0){
    double s = 0.0;
    for (int t = 0; t < 128; ++t) s += red[t];
    normS = sqrt(s);
  }
  __syncthreads();
  if (tid < nent)
    ws[W3J_OFF + k*128 + tid] = (float)(re / normS * sqrt((double)(2*l3+1)));  // fold sqrt(2l3+1)
}

// ---------------------------------------------------------------- node transform
// h[n][512]: [0..128) = h0[v]; [128 + i*128 + v] = h1[n][v][i]
__launch_bounds__(256, 4)
__global__ void node_kernel(const float* __restrict__ nf, const float* __restrict__ W0,
                            const float* __restrict__ W1, float* __restrict__ ws){
  __shared__ float AtL[128*68];
  float* h = ws + H_OFF;
  int tid = threadIdx.x;
  int n0 = blockIdx.x * 64;
  const float rs = 0.08838834764831845f; // 1/sqrt(128)
  int mg = (tid & 15) * 4;
  int vg = (tid >> 4) * 8;
  for (int c = 0; c < 4; ++c){
    __syncthreads();
    for (int idx = tid; idx < 8192; idx += 256){
      int m = idx >> 7, u = idx & 127;
      int node = n0 + m;
      float v = 0.f;
      if (node < NNODES)
        v = (c == 0) ? nf[(size_t)node*512 + u] : nf[(size_t)node*512 + 128 + u*3 + (c-1)];
      AtL[u*68 + m] = v;
    }
    __syncthreads();
    const float* W = (c == 0) ? W0 : W1;
    float acc[8][4];
    #pragma unroll
    for (int a = 0; a < 8; ++a){ acc[a][0]=0.f; acc[a][1]=0.f; acc[a][2]=0.f; acc[a][3]=0.f; }
    for (int u = 0; u < 128; ++u){
      float4 am = *(const float4*)&AtL[u*68 + mg];
      const float* wr = W + u*128 + vg;
      float4 b0 = *(const float4*)wr;
      float4 b1 = *(const float4*)(wr + 4);
      float aa[4] = {am.x, am.y, am.z, am.w};
      float bb[8] = {b0.x,b0.y,b0.z,b0.w,b1.x,b1.y,b1.z,b1.w};
      #pragma unroll
      for (int a = 0; a < 8; ++a)
        #pragma unroll
        for (int e = 0; e < 4; ++e)
          acc[a][e] += bb[a]*aa[e];
    }
    #pragma unroll
    for (int e = 0; e < 4; ++e){
      int node = n0 + mg + e;
      if (node < NNODES){
        float4 s0 = {acc[0][e]*rs, acc[1][e]*rs, acc[2][e]*rs, acc[3][e]*rs};
        float4 s1 = {acc[4][e]*rs, acc[5][e]*rs, acc[6][e]*rs, acc[7][e]*rs};
        *(float4*)&h[(size_t)node*512 + c*128 + vg] = s0;
        *(float4*)&h[(size_t)node*512 + c*128 + vg + 4] = s1;
      }
    }
  }
}

// ---------------------------------------------------------------- radial MLP (r2)
template<int KDIM>
__device__ __forceinline__ void mlp_layer(const float* __restrict__ Wg, const float* aL,
                                          float* oL, int tid, float scale){
  int eg = (tid & 15) * 4;
  int jg = (tid >> 4) * 4;
  float acc[4][4];
  #pragma unroll
  for (int a = 0; a < 4; ++a){ acc[a][0]=0.f; acc[a][1]=0.f; acc[a][2]=0.f; acc[a][3]=0.f; }
  #pragma unroll 4
  for (int i = 0; i < KDIM; ++i){
    float4 a4 = *(const float4*)&aL[i*68 + eg];
    float4 b4 = *(const float4*)&Wg[i*64 + jg];
    float aa[4] = {a4.x,a4.y,a4.z,a4.w};
    float bb[4] = {b4.x,b4.y,b4.z,b4.w};
    #pragma unroll
    for (int a = 0; a < 4; ++a)
      #pragma unroll
      for (int e = 0; e < 4; ++e)
        acc[a][e] += bb[a]*aa[e];
  }
  #pragma unroll
  for (int a = 0; a < 4; ++a){
    float4 st;
    float x0 = acc[a][0]*scale; st.x = x0/(1.f + expf(-x0));
    float x1 = acc[a][1]*scale; st.y = x1/(1.f + expf(-x1));
    float x2 = acc[a][2]*scale; st.z = x2/(1.f + expf(-x2));
    float x3 = acc[a][3]*scale; st.w = x3/(1.f + expf(-x3));
    *(float4*)&oL[(jg+a)*68 + eg] = st;
  }
}

__launch_bounds__(256)
__global__ void r2_kernel(const float* __restrict__ ef,
                          const float* __restrict__ RW0, const float* __restrict__ RW1,
                          const float* __restrict__ RW2, float* __restrict__ wsf){
  __shared__ float bufA[64*68];
  __shared__ float bufB[64*68];
  __shared__ float r2T[64*68];
  float* R2 = wsf + R2_OFF;
  int tid = threadIdx.x;
  int eb = blockIdx.x * 64;
  float* efT = r2T;  // 8*68 fits; dead after layer 1
  for (int idx = tid; idx < 512; idx += 256){
    int e = idx >> 3, i2 = idx & 7;
    efT[i2*68 + e] = ef[(size_t)(eb+e)*8 + i2];
  }
  __syncthreads();
  mlp_layer<8 >(RW0, efT, bufA, tid, 0.35355339059327373f);
  __syncthreads();
  mlp_layer<64>(RW1, bufA, bufB, tid, 0.125f);
  __syncthreads();
  mlp_layer<64>(RW2, bufB, r2T, tid, 0.125f);
  __syncthreads();
  for (int idx = tid; idx < 4096; idx += 256){
    int e = idx >> 6, i = idx & 63;
    R2[((size_t)(eb+e) << 6) + i] = r2T[i*68 + e];
  }
}

// ---------------------------------------------------------------- cc kernel (edge-parallel)
__device__ __forceinline__ float cc_compute(int r, const float* w3L, const float* she){
  float v = 0.f;
  #pragma unroll
  for (int in = 0; in < 10; ++in){
    if (r >= cCCO[in] && r < cCCO[in+1]){
      int rr = r - cCCO[in];
      const int N3v = cN3[in];
      const int N2v = 2*cL2[in] + 1;
      int i = rr / N3v;
      int q = rr - i*N3v;
      float s = 0.f;
      for (int j = 0; j < N2v; ++j)
        s += w3L[in*128 + (i*N2v + j)*N3v + q] * she[cSHO[in] + j];
      v = s;
    }
  }
  return v;
}

__launch_bounds__(256)
__global__ void cc_kernel(const float* __restrict__ ea, float* __restrict__ wsf){
  __shared__ float w3L[1280];
  __shared__ float shE[32*16];
  float* ccG = wsf + CC_OFF;
  int tid = threadIdx.x;
  int eb = blockIdx.x * 32;
  for (int idx = tid; idx < 1280; idx += 256) w3L[idx] = wsf[W3J_OFF + idx];
  for (int idx = tid; idx < 512; idx += 256){
    int e = idx >> 4, j = idx & 15;
    shE[e*16 + j] = ea[((size_t)(eb+e) << 4) + j];
  }
  __syncthreads();
  for (int idx = tid; idx < 32*88; idx += 256){
    int e = idx / 88, r = idx - e*88;
    ccG[(size_t)(eb+e)*88 + r] = cc_compute(r, w3L, shE + e*16);
  }
}

// ---------------------------------------------------------------- CSR build
__global__ void hist_kernel(const int* __restrict__ ei, int* __restrict__ cnt){
  int e = blockIdx.x*256 + threadIdx.x;
  if (e < NEDGES) atomicAdd(&cnt[ei[NEDGES + e]], 1);
}

__global__ void scan_kernel(const int* __restrict__ cnt, int* __restrict__ off){
  __shared__ int part[256];
  __shared__ int partp[256];
  int t = threadIdx.x;
  const int S = 40;  // 256*40 >= 10001
  int s = 0;
  for (int j = 0; j < S; ++j){ int idx = t*S + j; if (idx < NNODES) s += cnt[idx]; }
  part[t] = s;
  __syncthreads();
  if (t == 0){ int run = 0; for (int i = 0; i < 256; ++i){ partp[i] = run; run += part[i]; } }
  __syncthreads();
  int run = partp[t];
  for (int j = 0; j < S; ++j){
    int idx = t*S + j;
    if (idx <= NNODES){
      off[idx] = run;
      if (idx < NNODES) run += cnt[idx];
    }
  }
}

__global__ void fill_kernel(const int* __restrict__ ei, const int* __restrict__ off,
                            int* __restrict__ cur, int* __restrict__ elist){
  int e = blockIdx.x*256 + threadIdx.x;
  if (e < NEDGES){
    int r = ei[NEDGES + e];
    int p = off[r] + atomicAdd(&cur[r], 1);
    elist[p] = e;
  }
}

// ---------------------------------------------------------------- gather helpers
// TP for one edge, one instruction; h read directly from global (L2/L3-hot)
template<int IN>
__device__ __forceinline__ void tp_g(const float* __restrict__ cce, const float* __restrict__ hp,
                                     float wv, float* accm){
  constexpr int N3v = cN3[IN];
  if constexpr (cL1[IN] == 0){
    float wh = wv * hp[0];
    #pragma unroll
    for (int q = 0; q < N3v; ++q) accm[q] += cce[q] * wh;
  } else {
    float wa = wv * hp[128];
    float wb = wv * hp[256];
    float wc = wv * hp[384];
    #pragma unroll
    for (int q = 0; q < N3v; ++q)
      accm[q] += cce[q]*wa + cce[N3v+q]*wb + cce[2*N3v+q]*wc;
  }
}

// per instruction-pair M: w-GEMM (16-edge register tile) + TP accumulate
template<int M>
__device__ __forceinline__ void do_m(const float* __restrict__ RW3, const float* r2L,
                                     const float* ccL, const float* __restrict__ h,
                                     const int* sC, int tid, int u, int i0, float* accm){
  float wv[CHUNK];
  #pragma unroll
  for (int e = 0; e < CHUNK; ++e) wv[e] = 0.f;
  const float* rw = RW3 + 256*M + tid;
  #pragma unroll 4
  for (int i = 0; i < 64; ++i){
    float b = rw[(size_t)i*1280];
    const float* rr = &r2L[i*20];
    float4 r0 = *(const float4*)&rr[0];
    float4 r1 = *(const float4*)&rr[4];
    float4 r2v= *(const float4*)&rr[8];
    float4 r3 = *(const float4*)&rr[12];
    wv[0]  += b*r0.x;  wv[1]  += b*r0.y;  wv[2]  += b*r0.z;  wv[3]  += b*r0.w;
    wv[4]  += b*r1.x;  wv[5]  += b*r1.y;  wv[6]  += b*r1.z;  wv[7]  += b*r1.w;
    wv[8]  += b*r2v.x; wv[9]  += b*r2v.y; wv[10] += b*r2v.z; wv[11] += b*r2v.w;
    wv[12] += b*r3.x;  wv[13] += b*r3.y;  wv[14] += b*r3.z;  wv[15] += b*r3.w;
  }
  #pragma unroll
  for (int e = 0; e < CHUNK; ++e) wv[e] *= 0.125f;  // R_W3 / sqrt(64)
  // TP in two 8-edge halves (limits register spike from hoisted h loads)
  #pragma unroll
  for (int eh = 0; eh < 2; ++eh){
    if (i0 == 0){
      #pragma unroll
      for (int e8 = 0; e8 < 8; ++e8){
        int e = eh*8 + e8;
        const float* hp = h + ((size_t)sC[e] << 9) + u;
        tp_g<2*M>(ccL + e*88 + cCCO[2*M], hp, wv[e], accm);
      }
    } else {
      #pragma unroll
      for (int e8 = 0; e8 < 8; ++e8){
        int e = eh*8 + e8;
        const float* hp = h + ((size_t)sC[e] << 9) + u;
        tp_g<2*M+1>(ccL + e*88 + cCCO[2*M+1], hp, wv[e], accm);
      }
    }
  }
}

template<int IN>
__device__ __forceinline__ void st_cat(float* catL, int u, const float* accm){
  constexpr int N3v = cN3[IN];
  float* p = catL + cCATO[IN] + u*N3v;
  #pragma unroll
  for (int q = 0; q < N3v; ++q) p[q] = accm[q];
}

// output linear for one l, full K-range per thread (no cross-thread reduction)
template<int L>
__device__ __forceinline__ void out_l(const float* catL, const float* __restrict__ Wo,
                                      float* __restrict__ outp, int n, int v){
  constexpr int NI = 2*L + 1;
  constexpr int UL = (L==0 || L==3) ? 256 : 384;
  constexpr int GOv = (L==0) ? 0 : (L==1) ? 256 : (L==2) ? 1408 : 3328;
  constexpr int OOv = (L==0) ? 0 : (L==1) ? 1 : (L==2) ? 4 : 9;
  const float scale = (L==0 || L==3) ? 0.00390625f : 0.0031894435433133252f; // 1/(sqrt(UL)*16)
  float o[NI];
  #pragma unroll
  for (int i = 0; i < NI; ++i) o[i] = 0.f;
  #pragma unroll 4
  for (int ul = 0; ul < UL; ++ul){
    float wv = Wo[(size_t)ul*128 + v];
    const float* a = catL + GOv + ul*NI;   // broadcast LDS read (conflict-free)
    #pragma unroll
    for (int i = 0; i < NI; ++i) o[i] += a[i]*wv;
  }
  float* op = outp + (size_t)n*2048 + v*16 + OOv;
  #pragma unroll
  for (int i = 0; i < NI; ++i) op[i] = o[i]*scale;
}

// ---------------------------------------------------------------- gather kernel
// one block per receiver node; 16-edge chunks; cc precomputed per edge
__launch_bounds__(256, 7)
__global__ void gather_kernel(const int* __restrict__ ei,
                              const float* __restrict__ RW3,
                              const float* __restrict__ Wo0, const float* __restrict__ Wo1,
                              const float* __restrict__ Wo2, const float* __restrict__ Wo3,
                              const float* __restrict__ wsf,
                              const int* __restrict__ off, const int* __restrict__ elist,
                              float* __restrict__ outp){
  __shared__ float smemF[5120];          // 20.5 KB union
  // main-loop region
  int*   idsL = (int*)smemF;             // 512
  int*   idsC = (int*)(smemF + 512);     // 16
  int*   sC   = (int*)(smemF + 528);     // 16
  float* r2L  = smemF + 544;             // 64*20 = 1280 ([i][e], pad 20)
  float* ccL  = smemF + 1824;            // 16*88 = 1408  (ends 3232)
  // epilogue region (aliases everything above)
  float* catL = smemF;                   // 5120

  const float* h   = wsf + H_OFF;
  const float* R2  = wsf + R2_OFF;
  const float* ccG = wsf + CC_OFF;
  int nblk = blockIdx.x, tid = threadIdx.x;
  int beg = off[nblk], end = off[nblk+1];
  int deg = end - beg;
  int degc = deg < 512 ? deg : 512;
  for (int idx = tid; idx < degc; idx += 256) idsL[idx] = elist[beg + idx];
  __syncthreads();
  // rank-sort (edge ids distinct): deterministic accumulation order
  {
    int v0 = 0, r0 = 0, v1 = 0, r1 = 0;
    bool a0 = tid < degc, a1 = tid + 256 < degc;
    if (a0){ v0 = idsL[tid]; int r = 0; for (int j = 0; j < degc; ++j) r += (idsL[j] < v0); r0 = r; }
    if (a1){ v1 = idsL[tid+256]; int r = 0; for (int j = 0; j < degc; ++j) r += (idsL[j] < v1); r1 = r; }
    __syncthreads();
    if (a0) idsL[r0] = v0;
    if (a1) idsL[r1] = v1;
  }

  int u = tid & 127;
  int i0 = tid >> 7;           // 0 -> even instrs, 1 -> odd instrs (wave-uniform)
  float acc0[1] = {0.f};
  float acc1[3] = {0.f,0.f,0.f};
  float acc2[5] = {0.f,0.f,0.f,0.f,0.f};
  float acc3[5] = {0.f,0.f,0.f,0.f,0.f};
  float acc4[7] = {0.f,0.f,0.f,0.f,0.f,0.f,0.f};

  for (int base = 0; base < deg; base += CHUNK){
    int eN = deg - base; if (eN > CHUNK) eN = CHUNK;
    __syncthreads();  // protect LDS reuse vs previous chunk's reads
    if (tid < CHUNK){
      int k = base + tid;
      int id;
      if (tid < eN) id = (k < degc) ? idsL[k] : elist[beg + k];
      else          id = (base < degc) ? idsL[base] : elist[beg + base];  // pad: any valid edge
      idsC[tid] = id;
      sC[tid]   = ei[id];       // sender
    }
    __syncthreads();
    // r2 -> LDS transposed [i][e]; ZERO for pad edges (=> wv==0 kills their TP contribution)
    for (int idx = tid; idx < (CHUNK << 6); idx += 256){
      int e = idx >> 6, i = idx & 63;
      r2L[i*20 + e] = (e < eN) ? R2[((size_t)idsC[e] << 6) + i] : 0.f;
    }
    // cc -> LDS (coalesced rows; pad edges get valid-but-unused data, killed by wv==0)
    for (int idx = tid; idx < CHUNK*88; idx += 256){
      int e = idx / 88, r = idx - e*88;
      ccL[idx] = ccG[(size_t)idsC[e]*88 + r];
    }
    __syncthreads();
    // 5 instruction-pairs: w-GEMM (register tile) + TP accumulate (h direct from global)
    do_m<0>(RW3, r2L, ccL, h, sC, tid, u, i0, acc0);
    do_m<1>(RW3, r2L, ccL, h, sC, tid, u, i0, acc1);
    do_m<2>(RW3, r2L, ccL, h, sC, tid, u, i0, acc2);
    do_m<3>(RW3, r2L, ccL, h, sC, tid, u, i0, acc3);
    do_m<4>(RW3, r2L, ccL, h, sC, tid, u, i0, acc4);
  }
  __syncthreads();
  // epilogue: cat row -> LDS union, then fused output linear (split by l, no reduction)
  if (i0 == 0){
    st_cat<0>(catL, u, acc0);
    st_cat<2>(catL, u, acc1);
    st_cat<4>(catL, u, acc2);
    st_cat<6>(catL, u, acc3);
    st_cat<8>(catL, u, acc4);
  } else {
    st_cat<1>(catL, u, acc0);
    st_cat<3>(catL, u, acc1);
    st_cat<5>(catL, u, acc2);
    st_cat<7>(catL, u, acc3);
    st_cat<9>(catL, u, acc4);
  }
  __syncthreads();
  if (i0 == 0){
    out_l<0>(catL, Wo0, outp, nblk, u);
    out_l<2>(catL, Wo2, outp, nblk, u);
  } else {
    out_l<1>(catL, Wo1, outp, nblk, u);
    out_l<3>(catL, Wo3, outp, nblk, u);
  }
}

// ---------------------------------------------------------------- launch
extern "C" void kernel_launch(void* const* d_in, const int* in_sizes, int n_in,
                              void* d_out, int out_size, void* d_ws, size_t ws_size,
                              hipStream_t stream){
  const float* nf  = (const float*)d_in[0];
  const float* ea  = (const float*)d_in[2];
  const float* ef  = (const float*)d_in[3];
  const int*   ei  = (const int*)d_in[4];
  const float* W0  = (const float*)d_in[5];
  const float* W1  = (const float*)d_in[6];
  const float* RW0 = (const float*)d_in[7];
  const float* RW1 = (const float*)d_in[8];
  const float* RW2 = (const float*)d_in[9];
  const float* RW3 = (const float*)d_in[10];
  const float* Wo0 = (const float*)d_in[11];
  const float* Wo1 = (const float*)d_in[12];
  const float* Wo2 = (const float*)d_in[13];
  const float* Wo3 = (const float*)d_in[14];
  float* wsf  = (float*)d_ws;
  int*   wsi  = (int*)d_ws;
  float* outp = (float*)d_out;

  hipMemsetAsync(wsi + CNT_W, 0, 2*NNODES*sizeof(int), stream);  // cnt + cur
  w3j_kernel<<<10, 128, 0, stream>>>(wsf);
  node_kernel<<<157, 256, 0, stream>>>(nf, W0, W1, wsf);
  r2_kernel<<<2048, 256, 0, stream>>>(ef, RW0, RW1, RW2, wsf);
  cc_kernel<<<4096, 256, 0, stream>>>(ea, wsf);
  hist_kernel<<<512, 256, 0, stream>>>(ei, wsi + CNT_W);
  scan_kernel<<<1, 256, 0, stream>>>(wsi + CNT_W, wsi + OFF_W);
  fill_kernel<<<512, 256, 0, stream>>>(ei, wsi + OFF_W, wsi + CUR_W, wsi + ELIST_W);
  gather_kernel<<<NNODES, 256, 0, stream>>>(ei, RW3, Wo0, Wo1, Wo2, Wo3,
                                            wsf, wsi + OFF_W, wsi + ELIST_W, outp);
}